// Round 11
// baseline (1918.594 us; speedup 1.0000x reference)
//
#include <hip/hip_runtime.h>

typedef unsigned short ushort_t;
typedef __attribute__((ext_vector_type(8))) short bf16x8;
typedef __attribute__((ext_vector_type(4))) float f32x4;

#define BB 32
#define TT 64
#define HH 512
#define G4H 2048

__device__ __forceinline__ ushort_t f2bf(float f) {
    unsigned int u = __float_as_uint(f);
    unsigned int r = (u + 0x7fffu + ((u >> 16) & 1u)) >> 16;
    return (ushort_t)r;
}
__device__ __forceinline__ float sigf(float x) { return 1.f / (1.f + __expf(-x)); }
__device__ __forceinline__ float tanh_(float x) {
    float e = __expf(2.f * x);
    return 1.f - 2.f / (e + 1.f);
}

// ---------------- zero init (zeros vector for h0/c0) ----------------
__global__ void zero_init(float* zeros) {
    int t = threadIdx.x;
    if (t < 128) ((float4*)zeros)[t] = make_float4(0.f, 0.f, 0.f, 0.f); // 512 floats
}

// ---------------- embedding gather ----------------
__global__ void gather_rows(const int* __restrict__ idx, const float* __restrict__ emb,
                            float* __restrict__ out) {
    int row = blockIdx.x;      // 2048 rows
    int t = threadIdx.x;       // 64 threads
    int id = idx[row];
    float4 v = *(const float4*)(emb + (size_t)id * 256 + t * 4);
    *(float4*)(out + (size_t)row * 256 + t * 4) = v;
}

// ---------------- generic fp32 GEMM (tiny ctxW GEMM only) ----------------
__global__ __launch_bounds__(256) void gemm_f32(
    const float* __restrict__ A, int lda,
    const float* __restrict__ B, int ldb,
    const float* __restrict__ bias,
    void* __restrict__ Cv, int ldc,
    int M, int N, int K, int mode)
{
    __shared__ float As[16 * 68];
    __shared__ float Bs[16 * 68];
    const int tid = threadIdx.x;
    const int bm = blockIdx.y * 64, bn = blockIdx.x * 64;
    const int lr = tid >> 2, lk = (tid & 3) << 2;
    const int tr = (tid >> 4) << 2, tc = (tid & 15) << 2;
    float acc[4][4] = {};
    const int arow = bm + lr, brow = bn + lr;
    const bool aval = arow < M, bval = brow < N;
    const float* Ap = A + (size_t)arow * lda + lk;
    const float* Bp = B + (size_t)brow * ldb + lk;

    for (int k0 = 0; k0 < K; k0 += 16) {
        float4 av = make_float4(0.f, 0.f, 0.f, 0.f);
        float4 bv = make_float4(0.f, 0.f, 0.f, 0.f);
        if (aval) av = *(const float4*)(Ap + k0);
        if (bval) bv = *(const float4*)(Bp + k0);
        As[(lk + 0) * 68 + lr] = av.x; As[(lk + 1) * 68 + lr] = av.y;
        As[(lk + 2) * 68 + lr] = av.z; As[(lk + 3) * 68 + lr] = av.w;
        Bs[(lk + 0) * 68 + lr] = bv.x; Bs[(lk + 1) * 68 + lr] = bv.y;
        Bs[(lk + 2) * 68 + lr] = bv.z; Bs[(lk + 3) * 68 + lr] = bv.w;
        __syncthreads();
        #pragma unroll
        for (int kk = 0; kk < 16; kk++) {
            float4 a = *(const float4*)&As[kk * 68 + tr];
            float4 b = *(const float4*)&Bs[kk * 68 + tc];
            float ar[4] = {a.x, a.y, a.z, a.w};
            float br[4] = {b.x, b.y, b.z, b.w};
            #pragma unroll
            for (int i = 0; i < 4; i++)
                #pragma unroll
                for (int j = 0; j < 4; j++)
                    acc[i][j] = fmaf(ar[i], br[j], acc[i][j]);
        }
        __syncthreads();
    }
    #pragma unroll
    for (int i = 0; i < 4; i++) {
        int m = bm + tr + i;
        if (m >= M) continue;
        #pragma unroll
        for (int j = 0; j < 4; j++) {
            int n = bn + tc + j;
            if (n >= N) continue;
            float v = acc[i][j] + (bias ? bias[n] : 0.f);
            if (mode == 0) ((float*)Cv)[(size_t)m * ldc + n] = v;
            else ((ushort_t*)Cv)[(size_t)m * ldc + n] = f2bf(tanh_(v));
        }
    }
}

// ---------------- MFMA GEMM with f32->bf16 staging ----------------
__global__ __launch_bounds__(256) void gemm_mfma(
    const float* __restrict__ A, int lda,
    const float* __restrict__ B, int ldb,
    const float* __restrict__ bias,
    void* __restrict__ Cv, int ldc, int K, int mode)
{
    __shared__ ushort_t As[128 * 72];
    __shared__ ushort_t Bs[128 * 72];
    const int tid = threadIdx.x;
    const int bm = blockIdx.x * 128, bn = blockIdx.y * 128;
    const int lane = tid & 63, wave = tid >> 6;
    const int wm = (wave & 1) * 64, wn = (wave >> 1) * 64;
    const int lr = lane & 15, lk = (lane >> 4) * 8;
    const int srow = tid >> 3, sch = tid & 7;
    f32x4 acc[4][4] = {};

    for (int k0 = 0; k0 < K; k0 += 64) {
        #pragma unroll
        for (int rr = 0; rr < 4; rr++) {
            int row = srow + rr * 32;
            const float* as = A + (size_t)(bm + row) * lda + k0 + sch * 8;
            float4 a0 = *(const float4*)as;
            float4 a1 = *(const float4*)(as + 4);
            int4 pa;
            pa.x = (int)f2bf(a0.x) | ((int)f2bf(a0.y) << 16);
            pa.y = (int)f2bf(a0.z) | ((int)f2bf(a0.w) << 16);
            pa.z = (int)f2bf(a1.x) | ((int)f2bf(a1.y) << 16);
            pa.w = (int)f2bf(a1.z) | ((int)f2bf(a1.w) << 16);
            *(int4*)&As[row * 72 + sch * 8] = pa;
            const float* bs = B + (size_t)(bn + row) * ldb + k0 + sch * 8;
            float4 f0 = *(const float4*)bs;
            float4 f1 = *(const float4*)(bs + 4);
            int4 pk;
            pk.x = (int)f2bf(f0.x) | ((int)f2bf(f0.y) << 16);
            pk.y = (int)f2bf(f0.z) | ((int)f2bf(f0.w) << 16);
            pk.z = (int)f2bf(f1.x) | ((int)f2bf(f1.y) << 16);
            pk.w = (int)f2bf(f1.z) | ((int)f2bf(f1.w) << 16);
            *(int4*)&Bs[row * 72 + sch * 8] = pk;
        }
        __syncthreads();
        #pragma unroll
        for (int k2 = 0; k2 < 64; k2 += 32) {
            bf16x8 a[4], bfr[4];
            #pragma unroll
            for (int i = 0; i < 4; i++)
                a[i] = *(const bf16x8*)&As[(wm + i * 16 + lr) * 72 + k2 + lk];
            #pragma unroll
            for (int j = 0; j < 4; j++)
                bfr[j] = *(const bf16x8*)&Bs[(wn + j * 16 + lr) * 72 + k2 + lk];
            #pragma unroll
            for (int i = 0; i < 4; i++)
                #pragma unroll
                for (int j = 0; j < 4; j++)
                    acc[i][j] = __builtin_amdgcn_mfma_f32_16x16x32_bf16(a[i], bfr[j], acc[i][j], 0, 0, 0);
        }
        __syncthreads();
    }
    const int r0 = (lane >> 4) * 4;
    #pragma unroll
    for (int j = 0; j < 4; j++) {
        int col = bn + wn + j * 16 + lr;
        float bv = bias ? bias[col] : 0.f;
        #pragma unroll
        for (int i = 0; i < 4; i++) {
            int row = bm + wm + i * 16 + r0;
            #pragma unroll
            for (int q = 0; q < 4; q++) {
                float v = acc[i][j][q] + bv;
                if (mode == 0) ((float*)Cv)[(size_t)(row + q) * ldc + col] = v;
                else ((ushort_t*)Cv)[(size_t)(row + q) * ldc + col] = f2bf(tanh_(v));
            }
        }
    }
}

// ---------------- context mean ----------------
__global__ void mean_ctx(const float* __restrict__ e1, float* __restrict__ ctx) {
    int g = blockIdx.x * 256 + threadIdx.x; // 16384
    int b = g >> 9, u = g & 511;
    float s = 0.f;
    #pragma unroll 8
    for (int t = 0; t < TT; t++) s += e1[((size_t)b * TT + t) * HH + u];
    ctx[g] = s * (1.f / 64.f);
}

// ---- tagged poll primitives (v6-verified protocol; no token-pasting macros) ----
#define LOADS16                                                            \
        "global_load_dwordx2 %0, %16, off sc0 sc1\n\t"                     \
        "global_load_dwordx2 %1, %16, off offset:256 sc0 sc1\n\t"          \
        "global_load_dwordx2 %2, %16, off offset:512 sc0 sc1\n\t"          \
        "global_load_dwordx2 %3, %16, off offset:768 sc0 sc1\n\t"          \
        "global_load_dwordx2 %4, %16, off offset:1024 sc0 sc1\n\t"         \
        "global_load_dwordx2 %5, %16, off offset:1280 sc0 sc1\n\t"         \
        "global_load_dwordx2 %6, %16, off offset:1536 sc0 sc1\n\t"         \
        "global_load_dwordx2 %7, %16, off offset:1792 sc0 sc1\n\t"         \
        "global_load_dwordx2 %8, %16, off offset:2048 sc0 sc1\n\t"         \
        "global_load_dwordx2 %9, %16, off offset:2304 sc0 sc1\n\t"         \
        "global_load_dwordx2 %10, %16, off offset:2560 sc0 sc1\n\t"        \
        "global_load_dwordx2 %11, %16, off offset:2816 sc0 sc1\n\t"        \
        "global_load_dwordx2 %12, %16, off offset:3072 sc0 sc1\n\t"        \
        "global_load_dwordx2 %13, %16, off offset:3328 sc0 sc1\n\t"        \
        "global_load_dwordx2 %14, %16, off offset:3584 sc0 sc1\n\t"        \
        "global_load_dwordx2 %15, %16, off offset:3840 sc0 sc1\n\t"

#define OUTS16(a) "=&v"(a[0]), "=&v"(a[1]), "=&v"(a[2]), "=&v"(a[3]),      \
                  "=&v"(a[4]), "=&v"(a[5]), "=&v"(a[6]), "=&v"(a[7]),      \
                  "=&v"(a[8]), "=&v"(a[9]), "=&v"(a[10]), "=&v"(a[11]),    \
                  "=&v"(a[12]), "=&v"(a[13]), "=&v"(a[14]), "=&v"(a[15])

__device__ __forceinline__ bool tag_ok16(const uint2* q, unsigned int tag) {
    unsigned int a = 0xFFFFFFFFu, o = 0u;
    #pragma unroll
    for (int i = 0; i < 16; i++) { a &= q[i].x & q[i].y; o |= q[i].x | q[i].y; }
    return ((a >> 16) == tag) & ((o >> 16) == tag);
}

__device__ __forceinline__ void poll16_f32(const uint2* rp, unsigned int tag, float* hd) {
    uint2 q[16];
    bool ok;
    do {
        asm volatile(LOADS16 "s_waitcnt vmcnt(0)"
                     : OUTS16(q) : "v"(rp) : "memory");
        __builtin_amdgcn_sched_barrier(0);
        ok = tag_ok16(q, tag);
    } while (!ok);
    #pragma unroll
    for (int i = 0; i < 16; i++)
        hd[32 * i] = __uint_as_float((q[i].x << 16) | (q[i].y & 0xFFFFu));
}
__device__ __forceinline__ void poll16_bf16(const uint2* rp, unsigned int tag, ushort_t* hd) {
    uint2 q[16];
    bool ok;
    do {
        asm volatile(LOADS16 "s_waitcnt vmcnt(0)"
                     : OUTS16(q) : "v"(rp) : "memory");
        __builtin_amdgcn_sched_barrier(0);
        ok = tag_ok16(q, tag);
    } while (!ok);
    #pragma unroll
    for (int i = 0; i < 16; i++)
        hd[32 * i] = f2bf(__uint_as_float((q[i].x << 16) | (q[i].y & 0xFFFFu)));
}
// merged dual poll: 32 loads in flight, ONE waitcnt + sched fence, both tag sets checked
__device__ __forceinline__ void poll_dual(const uint2* rp1, unsigned int tag1, float* hd,
                                          const uint2* rp0, unsigned int tag0, ushort_t* ad) {
    uint2 q[16], r[16];
    bool ok;
    do {
        asm volatile(LOADS16 : OUTS16(q) : "v"(rp1) : "memory");
        asm volatile(LOADS16 "s_waitcnt vmcnt(0)"
                     : OUTS16(r) : "v"(rp0) : "memory");
        __builtin_amdgcn_sched_barrier(0);
        ok = tag_ok16(q, tag1) & tag_ok16(r, tag0);
    } while (!ok);
    #pragma unroll
    for (int i = 0; i < 16; i++) {
        hd[32 * i] = __uint_as_float((q[i].x << 16) | (q[i].y & 0xFFFFu));
        ad[32 * i] = f2bf(__uint_as_float((r[i].x << 16) | (r[i].y & 0xFFFFu)));
    }
}

// ---------------- fused layer-pair scan (v10) ----------------
// 256 blocks x 512 threads: blocks 0..127 = layer0, 128..255 = layer1.
// Dot roles: wave w = unit (0..7), lane l = batch(l>>2) x gate(l&3) quad; Whh rows
// stored at permuted LDS slots p = unit*4 + gate (conflict-free reads).
// Pointwise via 3x shfl_xor within the quad -> publish immediately after dot
// (no glds round-trip). L1: Wih1 x-proj via register-stationary bf16 MFMA (v9-verified),
// merged dual poll (one sweep for ring1 h1(t) + ring0 h0(t+1)).
__global__ __launch_bounds__(512) void scan_pair3(
    const float* __restrict__ gatesX0,
    const float* __restrict__ ctxAdd0,
    const float* __restrict__ Whh0,
    const float* __restrict__ Wih1,
    const float* __restrict__ Whh1,
    const float* __restrict__ b1,
    const float* __restrict__ h00, int sh00, const float* __restrict__ c00, int sc00,
    const float* __restrict__ h01, int sh01, const float* __restrict__ c01, int sc01,
    float* __restrict__ out0, float* __restrict__ out1,
    float* __restrict__ cT0o, float* __restrict__ cT1o,
    uint2* __restrict__ ring0, uint2* __restrict__ ring1,
    int tb0, int tb1)
{
    __shared__ float wlds[32 * 516];    // own-layer Whh, slot p = unit*4 + gate
    __shared__ float hmain[16 * 516];   // L0: h0(t-1); L1: h1(t-1)
    __shared__ ushort_t ah[16 * 520];   // L1: h0(t) bf16 (MFMA A-operand)
    __shared__ float pglds[8 * 256];    // L1: MFMA partials [kh*2+ni][batch*16+col]
    const int tid = threadIdx.x;
    const bool isL1 = blockIdx.x >= 128;
    const int rb = blockIdx.x & 127;
    const int bg = rb >> 6, ub = rb & 63, u0 = ub * 8;
    const int w = tid >> 6, l = tid & 63;
    const int bb = l >> 2, g = l & 3;               // batch 0..15, gate 0..3
    const int grow = g * HH + u0 + w;               // own gate row (unit = w)
    const int batch = bg * 16 + bb;
    const int srow = tid >> 5, hc0 = tid & 31;      // staging role

    { // stationary own-layer Whh -> LDS, slot sr holds (unit sr>>2, gate sr&3)
        const float* W = isL1 ? Whh1 : Whh0;
        const int sr = tid >> 4, ch = (tid & 15) * 32;
        const float* ws = W + (size_t)((sr & 3) * HH + u0 + (sr >> 2)) * HH + ch;
        float* wd = &wlds[sr * 516 + ch];
        #pragma unroll
        for (int j = 0; j < 32; j += 4) *(f32x4*)(wd + j) = *(const f32x4*)(ws + j);
    }
    // L1: stationary Wih1 bf16 B-fragments (v9-verified layout)
    const int ni = w & 1, kh = w >> 1, lr = l & 15, ls = l >> 4;
    bf16x8 bfrag[4];
    if (isL1) {
        const int nrow = ni * 16 + lr;
        const int gN = (nrow >> 3) * HH + u0 + (nrow & 7);
        const float* wr = Wih1 + (size_t)gN * HH + kh * 128 + ls * 8;
        #pragma unroll
        for (int kk = 0; kk < 4; kk++) {
            float f[8];
            *(f32x4*)&f[0] = *(const f32x4*)(wr + kk * 32);
            *(f32x4*)&f[4] = *(const f32x4*)(wr + kk * 32 + 4);
            bf16x8 hv;
            #pragma unroll
            for (int j = 0; j < 8; j++) hv[j] = (short)f2bf(f[j]);
            bfrag[kk] = hv;
        }
    }
    { // initial own-recurrence h -> hmain
        const float* hsrc = isL1 ? h01 : h00;
        const int hstr = isL1 ? sh01 : sh00;
        const float* hs = hsrc + (size_t)(bg * 16 + srow) * hstr;
        float* hd = &hmain[srow * 516 + hc0];
        #pragma unroll
        for (int j = 0; j < 16; j++) hd[32 * j] = hs[hc0 + 32 * j];
    }
    // per-lane state (quad-redundant c)
    float creg;
    {
        const float* ci = isL1 ? c01 : c00;
        const int cs = isL1 ? sc01 : sc00;
        creg = ci[(size_t)batch * cs + u0 + w];
    }
    float b1v = 0.f, xctx = 0.f, gx_cur = 0.f, gx_nxt = 0.f;
    const float* gxp = nullptr;
    if (!isL1) {
        gxp = gatesX0 + (size_t)batch * TT * G4H + grow;
        gx_cur = gxp[0];
        if (ctxAdd0) xctx = ctxAdd0[(size_t)batch * G4H + grow];
    } else {
        b1v = b1[grow];
        const uint2* rp = ring0 + ((size_t)0 * BB + bg * 16 + srow) * HH + hc0;
        poll16_bf16(rp, (unsigned int)(tb0 + 1), &ah[srow * 520 + hc0]);
    }
    float* outp = isL1 ? out1 : out0;
    uint2* ringp = isL1 ? ring1 : ring0;
    const int tbase = isL1 ? tb1 : tb0;
    const float* wp = &wlds[(w * 4 + g) * 516];

    for (int t = 0; t < TT; ++t) {
        __syncthreads();   // staged inputs ready
        float pre;
        if (!isL1) {
            int tn = (t + 1 < TT) ? t + 1 : t;
            gx_nxt = gxp[(size_t)tn * G4H];
            f32x4 s = {0.f, 0.f, 0.f, 0.f};
            const float* hp = &hmain[bb * 516];
            #pragma unroll 8
            for (int k = 0; k < HH; k += 4) {
                f32x4 hv = *(const f32x4*)(hp + k);
                f32x4 wv = *(const f32x4*)(wp + k);
                s.x = fmaf(hv.x, wv.x, s.x); s.y = fmaf(hv.y, wv.y, s.y);
                s.z = fmaf(hv.z, wv.z, s.z); s.w = fmaf(hv.w, wv.w, s.w);
            }
            pre = gx_cur + xctx + ((s.x + s.y) + (s.z + s.w));
        } else {
            // x-projection MFMA partials
            f32x4 acc = {0.f, 0.f, 0.f, 0.f};
            const ushort_t* ab = &ah[lr * 520 + kh * 128 + ls * 8];
            #pragma unroll
            for (int kk = 0; kk < 4; kk++) {
                bf16x8 av = *(const bf16x8*)(ab + kk * 32);
                acc = __builtin_amdgcn_mfma_f32_16x16x32_bf16(av, bfrag[kk], acc, 0, 0, 0);
            }
            #pragma unroll
            for (int q = 0; q < 4; q++)
                pglds[(kh * 2 + ni) * 256 + (ls * 4 + q) * 16 + lr] = acc[q];
            // recurrent h-dot (fp32)
            f32x4 s = {0.f, 0.f, 0.f, 0.f};
            const float* hp = &hmain[bb * 516];
            #pragma unroll 8
            for (int k = 0; k < HH; k += 4) {
                f32x4 hv = *(const f32x4*)(hp + k);
                f32x4 wv = *(const f32x4*)(wp + k);
                s.x = fmaf(hv.x, wv.x, s.x); s.y = fmaf(hv.y, wv.y, s.y);
                s.z = fmaf(hv.z, wv.z, s.z); s.w = fmaf(hv.w, wv.w, s.w);
            }
            pre = b1v + ((s.x + s.y) + (s.z + s.w));
            __syncthreads();   // pglds ready
            #pragma unroll
            for (int k2 = 0; k2 < 4; k2++)
                pre += pglds[(k2 * 2 + (g >> 1)) * 256 + bb * 16 + (g & 1) * 8 + w];
        }
        // quad exchange of the 4 gate pre-activations
        float x1 = __shfl_xor(pre, 1);
        float x2 = __shfl_xor(pre, 2);
        float x3 = __shfl_xor(x1, 2);
        const bool isG0 = (g == 0), isG1 = (g == 1), isG2 = (g == 2), isG3 = (g == 3);
        float pi = isG0 ? pre : (isG1 ? x1 : (isG2 ? x2 : x3));
        float pf = isG1 ? pre : (isG0 ? x1 : (isG3 ? x2 : x3));
        float pg = isG2 ? pre : (isG3 ? x1 : (isG0 ? x2 : x3));
        float po = isG3 ? pre : (isG2 ? x1 : (isG1 ? x2 : x3));
        float c = sigf(pf) * creg + sigf(pi) * tanh_(pg);
        float h = sigf(po) * tanh_(c);
        creg = c;
        const unsigned int tag = (unsigned int)(tbase + t + 1);
        if (isG0) {
            unsigned int hu = __float_as_uint(h);
            uint2 wv2;
            wv2.x = (tag << 16) | (hu >> 16);
            wv2.y = (tag << 16) | (hu & 0xFFFFu);
            uint2* pp = ringp + ((size_t)t * BB + batch) * HH + u0 + w;
            asm volatile("global_store_dwordx2 %0, %1, off sc0 sc1"
                         :: "v"(pp), "v"(wv2) : "memory");
            outp[((size_t)batch * TT + t) * HH + u0 + w] = h;
            if (t == TT - 1) {
                if (!isL1 && cT0o) cT0o[(size_t)batch * HH + u0 + w] = c;
                if (isL1 && cT1o)  cT1o[(size_t)batch * HH + u0 + w] = c;
            }
        }
        __syncthreads();   // all hmain reads done; safe to restage
        if (t + 1 < TT) {
            if (!isL1) {
                const uint2* rp = ring0 + ((size_t)t * BB + bg * 16 + srow) * HH + hc0;
                poll16_f32(rp, tag, &hmain[srow * 516 + hc0]);
            } else {
                const uint2* rp1 = ring1 + ((size_t)t * BB + bg * 16 + srow) * HH + hc0;
                const uint2* rp0 = ring0 + ((size_t)(t + 1) * BB + bg * 16 + srow) * HH + hc0;
                poll_dual(rp1, tag, &hmain[srow * 516 + hc0],
                          rp0, (unsigned int)(tb0 + t + 2), &ah[srow * 520 + hc0]);
            }
        }
        gx_cur = gx_nxt;
    }
}

// ---------------- final projection: bf16 MFMA GEMM, C = A*B^T + bias ----------------
__global__ __launch_bounds__(256) void gemm_bf16(
    const ushort_t* __restrict__ A,
    const float* __restrict__ B,
    const float* __restrict__ bias,
    float* __restrict__ C, int M, int N, int K)
{
    __shared__ ushort_t As[128 * 72];
    __shared__ ushort_t Bs[128 * 72];
    const int tid = threadIdx.x;
    const int bm = blockIdx.x * 128, bn = blockIdx.y * 128;
    const int lane = tid & 63, wave = tid >> 6;
    const int wm = (wave & 1) * 64, wn = (wave >> 1) * 64;
    const int lr = lane & 15, lk = (lane >> 4) * 8;
    const int srow = tid >> 3, sch = tid & 7;
    f32x4 acc[4][4] = {};

    for (int k0 = 0; k0 < K; k0 += 64) {
        #pragma unroll
        for (int rr = 0; rr < 4; rr++) {
            int row = srow + rr * 32;
            const ushort_t* as = A + (size_t)(bm + row) * K + k0 + sch * 8;
            *(int4*)&As[row * 72 + sch * 8] = *(const int4*)as;
            const float* bs = B + (size_t)(bn + row) * K + k0 + sch * 8;
            float4 f0 = *(const float4*)bs;
            float4 f1 = *(const float4*)(bs + 4);
            int4 pk;
            pk.x = (int)f2bf(f0.x) | ((int)f2bf(f0.y) << 16);
            pk.y = (int)f2bf(f0.z) | ((int)f2bf(f0.w) << 16);
            pk.z = (int)f2bf(f1.x) | ((int)f2bf(f1.y) << 16);
            pk.w = (int)f2bf(f1.z) | ((int)f2bf(f1.w) << 16);
            *(int4*)&Bs[row * 72 + sch * 8] = pk;
        }
        __syncthreads();
        #pragma unroll
        for (int k2 = 0; k2 < 64; k2 += 32) {
            bf16x8 a[4], bfr[4];
            #pragma unroll
            for (int i = 0; i < 4; i++)
                a[i] = *(const bf16x8*)&As[(wm + i * 16 + lr) * 72 + k2 + lk];
            #pragma unroll
            for (int j = 0; j < 4; j++)
                bfr[j] = *(const bf16x8*)&Bs[(wn + j * 16 + lr) * 72 + k2 + lk];
            #pragma unroll
            for (int i = 0; i < 4; i++)
                #pragma unroll
                for (int j = 0; j < 4; j++)
                    acc[i][j] = __builtin_amdgcn_mfma_f32_16x16x32_bf16(a[i], bfr[j], acc[i][j], 0, 0, 0);
        }
        __syncthreads();
    }
    const int r0 = (lane >> 4) * 4;
    #pragma unroll
    for (int j = 0; j < 4; j++) {
        int col = bn + wn + j * 16 + lr;
        float bv = bias[col];
        #pragma unroll
        for (int i = 0; i < 4; i++) {
            int row = bm + wm + i * 16 + r0;
            #pragma unroll
            for (int q = 0; q < 4; q++)
                C[(size_t)(row + q) * N + col] = acc[i][j][q] + bv;
        }
    }
}

extern "C" void kernel_launch(void* const* d_in, const int* in_sizes, int n_in,
                              void* d_out, int out_size, void* d_ws, size_t ws_size,
                              hipStream_t stream) {
    const int*   src      = (const int*)d_in[0];
    const int*   tgt      = (const int*)d_in[1];
    const float* enc_emb  = (const float*)d_in[2];
    const float* dec_emb  = (const float*)d_in[3];
    const float* eWih0    = (const float*)d_in[4];
    const float* eWhh0    = (const float*)d_in[5];
    const float* eb0      = (const float*)d_in[6];
    const float* eWih1    = (const float*)d_in[7];
    const float* eWhh1    = (const float*)d_in[8];
    const float* eb1      = (const float*)d_in[9];
    const float* dWih0    = (const float*)d_in[10];
    const float* dWhh0    = (const float*)d_in[11];
    const float* db0      = (const float*)d_in[12];
    const float* dWih1    = (const float*)d_in[13];
    const float* dWhh1    = (const float*)d_in[14];
    const float* db1      = (const float*)d_in[15];
    const float* pW1      = (const float*)d_in[16];
    const float* pb1      = (const float*)d_in[17];
    const float* pW2      = (const float*)d_in[18];
    const float* pb2      = (const float*)d_in[19];
    float* out = (float*)d_out;

    // workspace carve (small persistent buffers)
    float* fws   = (float*)d_ws;
    float* zeros = fws;                        // 512 f (padded to 1024)
    float* cT0   = fws + 2048;                 // 16384 f
    float* cT1   = cT0 + 16384;
    float* ctx   = cT1 + 16384;
    float* ctxW  = ctx + 16384;                // 65536 f
    ushort_t* hid = (ushort_t*)(ctxW + 65536); // 2048*512 bf16

    // d_out scratch (all dead before final projection writes everything)
    float* G0  = out;                 // 2048*2048 gate buffers
    float* G1  = G0 + 4194304;        // (unused; layout kept)
    float* G2  = G1 + 4194304;
    float* G3  = G2 + 4194304;        // (unused)
    float* xe  = G3 + 4194304;        // 2048*256
    float* xd  = xe + 524288;
    float* e0  = xd + 524288;         // 2048*512
    float* e1  = e0 + 1048576;
    float* d0  = e1 + 1048576;
    float* d1v = d0 + 1048576;
    uint2* ring0 = (uint2*)(d1v + 1048576);  // [64][32][512] tagged h (8 MB)
    uint2* ring1 = ring0 + 1048576;          // [64][32][512] tagged h (8 MB)

    zero_init<<<1, 256, 0, stream>>>(zeros);
    gather_rows<<<2048, 64, 0, stream>>>(src, enc_emb, xe);
    gather_rows<<<2048, 64, 0, stream>>>(tgt, dec_emb, xd);

    // layer-0 input projections (K=256, MFMA)
    gemm_mfma<<<dim3(16, 16), 256, 0, stream>>>(xe, 256, eWih0, 256, eb0, G0, 2048, 256, 0);
    gemm_mfma<<<dim3(16, 16), 256, 0, stream>>>(xd, 256, dWih0, 768, db0, G2, 2048, 256, 0);

    // fused encoder pair (enc0 + enc1 pipelined, skew 1)
    scan_pair3<<<256, 512, 0, stream>>>(
        G0, nullptr, eWhh0, eWih1, eWhh1, eb1,
        zeros, 0, zeros, 0, zeros, 0, zeros, 0,
        e0, e1, cT0, cT1, ring0, ring1, 0, 64);

    // context
    mean_ctx<<<64, 256, 0, stream>>>(e1, ctx);
    gemm_f32<<<dim3(32, 1), 256, 0, stream>>>(ctx, 512, dWih0 + 256, 768, nullptr, ctxW, 2048, 32, 2048, 512, 0);

    // fused decoder pair
    scan_pair3<<<256, 512, 0, stream>>>(
        G2, ctxW, dWhh0, dWih1, dWhh1, db1,
        e0 + 63 * 512, 64 * 512, cT0, 512,
        e1 + 63 * 512, 64 * 512, cT1, 512,
        d0, d1v, nullptr, nullptr, ring0, ring1, 128, 192);

    // projection: hid = tanh(d1*W1^T + b1) (MFMA, bf16 out); logits = hid*W2^T + b2
    gemm_mfma<<<dim3(16, 4), 256, 0, stream>>>(d1v, 512, pW1, 512, pb1, hid, 512, 512, 2);
    gemm_bf16<<<dim3(16, 250), 256, 0, stream>>>(hid, pW2, pb2, out, 2048, 32000, 512);
}

// Round 12
// 1736.628 us; speedup vs baseline: 1.1048x; 1.1048x over previous
//
#include <hip/hip_runtime.h>

typedef unsigned short ushort_t;
typedef __attribute__((ext_vector_type(8))) short bf16x8;
typedef __attribute__((ext_vector_type(4))) float f32x4;

#define BB 32
#define TT 64
#define HH 512
#define G4H 2048

__device__ __forceinline__ ushort_t f2bf(float f) {
    unsigned int u = __float_as_uint(f);
    unsigned int r = (u + 0x7fffu + ((u >> 16) & 1u)) >> 16;
    return (ushort_t)r;
}
__device__ __forceinline__ float sigf(float x) { return 1.f / (1.f + __expf(-x)); }
__device__ __forceinline__ float tanh_(float x) {
    float e = __expf(2.f * x);
    return 1.f - 2.f / (e + 1.f);
}

// ---------------- zero init (zeros vector for h0/c0) ----------------
__global__ void zero_init(float* zeros) {
    int t = threadIdx.x;
    if (t < 128) ((float4*)zeros)[t] = make_float4(0.f, 0.f, 0.f, 0.f); // 512 floats
}

// ---------------- embedding gather ----------------
__global__ void gather_rows(const int* __restrict__ idx, const float* __restrict__ emb,
                            float* __restrict__ out) {
    int row = blockIdx.x;      // 2048 rows
    int t = threadIdx.x;       // 64 threads
    int id = idx[row];
    float4 v = *(const float4*)(emb + (size_t)id * 256 + t * 4);
    *(float4*)(out + (size_t)row * 256 + t * 4) = v;
}

// ---------------- generic fp32 GEMM (tiny ctxW GEMM only) ----------------
__global__ __launch_bounds__(256) void gemm_f32(
    const float* __restrict__ A, int lda,
    const float* __restrict__ B, int ldb,
    const float* __restrict__ bias,
    void* __restrict__ Cv, int ldc,
    int M, int N, int K, int mode)
{
    __shared__ float As[16 * 68];
    __shared__ float Bs[16 * 68];
    const int tid = threadIdx.x;
    const int bm = blockIdx.y * 64, bn = blockIdx.x * 64;
    const int lr = tid >> 2, lk = (tid & 3) << 2;
    const int tr = (tid >> 4) << 2, tc = (tid & 15) << 2;
    float acc[4][4] = {};
    const int arow = bm + lr, brow = bn + lr;
    const bool aval = arow < M, bval = brow < N;
    const float* Ap = A + (size_t)arow * lda + lk;
    const float* Bp = B + (size_t)brow * ldb + lk;

    for (int k0 = 0; k0 < K; k0 += 16) {
        float4 av = make_float4(0.f, 0.f, 0.f, 0.f);
        float4 bv = make_float4(0.f, 0.f, 0.f, 0.f);
        if (aval) av = *(const float4*)(Ap + k0);
        if (bval) bv = *(const float4*)(Bp + k0);
        As[(lk + 0) * 68 + lr] = av.x; As[(lk + 1) * 68 + lr] = av.y;
        As[(lk + 2) * 68 + lr] = av.z; As[(lk + 3) * 68 + lr] = av.w;
        Bs[(lk + 0) * 68 + lr] = bv.x; Bs[(lk + 1) * 68 + lr] = bv.y;
        Bs[(lk + 2) * 68 + lr] = bv.z; Bs[(lk + 3) * 68 + lr] = bv.w;
        __syncthreads();
        #pragma unroll
        for (int kk = 0; kk < 16; kk++) {
            float4 a = *(const float4*)&As[kk * 68 + tr];
            float4 b = *(const float4*)&Bs[kk * 68 + tc];
            float ar[4] = {a.x, a.y, a.z, a.w};
            float br[4] = {b.x, b.y, b.z, b.w};
            #pragma unroll
            for (int i = 0; i < 4; i++)
                #pragma unroll
                for (int j = 0; j < 4; j++)
                    acc[i][j] = fmaf(ar[i], br[j], acc[i][j]);
        }
        __syncthreads();
    }
    #pragma unroll
    for (int i = 0; i < 4; i++) {
        int m = bm + tr + i;
        if (m >= M) continue;
        #pragma unroll
        for (int j = 0; j < 4; j++) {
            int n = bn + tc + j;
            if (n >= N) continue;
            float v = acc[i][j] + (bias ? bias[n] : 0.f);
            if (mode == 0) ((float*)Cv)[(size_t)m * ldc + n] = v;
            else ((ushort_t*)Cv)[(size_t)m * ldc + n] = f2bf(tanh_(v));
        }
    }
}

// ---------------- MFMA GEMM with f32->bf16 staging ----------------
__global__ __launch_bounds__(256) void gemm_mfma(
    const float* __restrict__ A, int lda,
    const float* __restrict__ B, int ldb,
    const float* __restrict__ bias,
    void* __restrict__ Cv, int ldc, int K, int mode)
{
    __shared__ ushort_t As[128 * 72];
    __shared__ ushort_t Bs[128 * 72];
    const int tid = threadIdx.x;
    const int bm = blockIdx.x * 128, bn = blockIdx.y * 128;
    const int lane = tid & 63, wave = tid >> 6;
    const int wm = (wave & 1) * 64, wn = (wave >> 1) * 64;
    const int lr = lane & 15, lk = (lane >> 4) * 8;
    const int srow = tid >> 3, sch = tid & 7;
    f32x4 acc[4][4] = {};

    for (int k0 = 0; k0 < K; k0 += 64) {
        #pragma unroll
        for (int rr = 0; rr < 4; rr++) {
            int row = srow + rr * 32;
            const float* as = A + (size_t)(bm + row) * lda + k0 + sch * 8;
            float4 a0 = *(const float4*)as;
            float4 a1 = *(const float4*)(as + 4);
            int4 pa;
            pa.x = (int)f2bf(a0.x) | ((int)f2bf(a0.y) << 16);
            pa.y = (int)f2bf(a0.z) | ((int)f2bf(a0.w) << 16);
            pa.z = (int)f2bf(a1.x) | ((int)f2bf(a1.y) << 16);
            pa.w = (int)f2bf(a1.z) | ((int)f2bf(a1.w) << 16);
            *(int4*)&As[row * 72 + sch * 8] = pa;
            const float* bs = B + (size_t)(bn + row) * ldb + k0 + sch * 8;
            float4 f0 = *(const float4*)bs;
            float4 f1 = *(const float4*)(bs + 4);
            int4 pk;
            pk.x = (int)f2bf(f0.x) | ((int)f2bf(f0.y) << 16);
            pk.y = (int)f2bf(f0.z) | ((int)f2bf(f0.w) << 16);
            pk.z = (int)f2bf(f1.x) | ((int)f2bf(f1.y) << 16);
            pk.w = (int)f2bf(f1.z) | ((int)f2bf(f1.w) << 16);
            *(int4*)&Bs[row * 72 + sch * 8] = pk;
        }
        __syncthreads();
        #pragma unroll
        for (int k2 = 0; k2 < 64; k2 += 32) {
            bf16x8 a[4], bfr[4];
            #pragma unroll
            for (int i = 0; i < 4; i++)
                a[i] = *(const bf16x8*)&As[(wm + i * 16 + lr) * 72 + k2 + lk];
            #pragma unroll
            for (int j = 0; j < 4; j++)
                bfr[j] = *(const bf16x8*)&Bs[(wn + j * 16 + lr) * 72 + k2 + lk];
            #pragma unroll
            for (int i = 0; i < 4; i++)
                #pragma unroll
                for (int j = 0; j < 4; j++)
                    acc[i][j] = __builtin_amdgcn_mfma_f32_16x16x32_bf16(a[i], bfr[j], acc[i][j], 0, 0, 0);
        }
        __syncthreads();
    }
    const int r0 = (lane >> 4) * 4;
    #pragma unroll
    for (int j = 0; j < 4; j++) {
        int col = bn + wn + j * 16 + lr;
        float bv = bias ? bias[col] : 0.f;
        #pragma unroll
        for (int i = 0; i < 4; i++) {
            int row = bm + wm + i * 16 + r0;
            #pragma unroll
            for (int q = 0; q < 4; q++) {
                float v = acc[i][j][q] + bv;
                if (mode == 0) ((float*)Cv)[(size_t)(row + q) * ldc + col] = v;
                else ((ushort_t*)Cv)[(size_t)(row + q) * ldc + col] = f2bf(tanh_(v));
            }
        }
    }
}

// ---------------- context mean ----------------
__global__ void mean_ctx(const float* __restrict__ e1, float* __restrict__ ctx) {
    int g = blockIdx.x * 256 + threadIdx.x; // 16384
    int b = g >> 9, u = g & 511;
    float s = 0.f;
    #pragma unroll 8
    for (int t = 0; t < TT; t++) s += e1[((size_t)b * TT + t) * HH + u];
    ctx[g] = s * (1.f / 64.f);
}

// ---- tagged poll primitives (v6-verified protocol; array-operand macros) ----
#define LOADS16                                                            \
        "global_load_dwordx2 %0, %16, off sc0 sc1\n\t"                     \
        "global_load_dwordx2 %1, %16, off offset:256 sc0 sc1\n\t"          \
        "global_load_dwordx2 %2, %16, off offset:512 sc0 sc1\n\t"          \
        "global_load_dwordx2 %3, %16, off offset:768 sc0 sc1\n\t"          \
        "global_load_dwordx2 %4, %16, off offset:1024 sc0 sc1\n\t"         \
        "global_load_dwordx2 %5, %16, off offset:1280 sc0 sc1\n\t"         \
        "global_load_dwordx2 %6, %16, off offset:1536 sc0 sc1\n\t"         \
        "global_load_dwordx2 %7, %16, off offset:1792 sc0 sc1\n\t"         \
        "global_load_dwordx2 %8, %16, off offset:2048 sc0 sc1\n\t"         \
        "global_load_dwordx2 %9, %16, off offset:2304 sc0 sc1\n\t"         \
        "global_load_dwordx2 %10, %16, off offset:2560 sc0 sc1\n\t"        \
        "global_load_dwordx2 %11, %16, off offset:2816 sc0 sc1\n\t"        \
        "global_load_dwordx2 %12, %16, off offset:3072 sc0 sc1\n\t"        \
        "global_load_dwordx2 %13, %16, off offset:3328 sc0 sc1\n\t"        \
        "global_load_dwordx2 %14, %16, off offset:3584 sc0 sc1\n\t"        \
        "global_load_dwordx2 %15, %16, off offset:3840 sc0 sc1\n\t"

#define OUTS16(a) "=&v"(a[0]), "=&v"(a[1]), "=&v"(a[2]), "=&v"(a[3]),      \
                  "=&v"(a[4]), "=&v"(a[5]), "=&v"(a[6]), "=&v"(a[7]),      \
                  "=&v"(a[8]), "=&v"(a[9]), "=&v"(a[10]), "=&v"(a[11]),    \
                  "=&v"(a[12]), "=&v"(a[13]), "=&v"(a[14]), "=&v"(a[15])

__device__ __forceinline__ bool tag_ok16(const uint2* q, unsigned int tag) {
    unsigned int a = 0xFFFFFFFFu, o = 0u;
    #pragma unroll
    for (int i = 0; i < 16; i++) { a &= q[i].x & q[i].y; o |= q[i].x | q[i].y; }
    return ((a >> 16) == tag) & ((o >> 16) == tag);
}

__device__ __forceinline__ void poll16_f32(const uint2* rp, unsigned int tag, float* hd) {
    uint2 q[16];
    bool ok;
    do {
        asm volatile(LOADS16 "s_waitcnt vmcnt(0)"
                     : OUTS16(q) : "v"(rp) : "memory");
        __builtin_amdgcn_sched_barrier(0);
        ok = tag_ok16(q, tag);
    } while (!ok);
    #pragma unroll
    for (int i = 0; i < 16; i++)
        hd[32 * i] = __uint_as_float((q[i].x << 16) | (q[i].y & 0xFFFFu));
}
__device__ __forceinline__ void poll16_bf16(const uint2* rp, unsigned int tag, ushort_t* hd) {
    uint2 q[16];
    bool ok;
    do {
        asm volatile(LOADS16 "s_waitcnt vmcnt(0)"
                     : OUTS16(q) : "v"(rp) : "memory");
        __builtin_amdgcn_sched_barrier(0);
        ok = tag_ok16(q, tag);
    } while (!ok);
    #pragma unroll
    for (int i = 0; i < 16; i++)
        hd[32 * i] = f2bf(__uint_as_float((q[i].x << 16) | (q[i].y & 0xFFFFu)));
}
// merged dual poll: 32 loads in flight, ONE waitcnt + sched fence, both tag sets checked
// (correctness proven in round-11 run)
__device__ __forceinline__ void poll_dual(const uint2* rp1, unsigned int tag1, float* hd,
                                          const uint2* rp0, unsigned int tag0, ushort_t* ad) {
    uint2 q[16], r[16];
    bool ok;
    do {
        asm volatile(LOADS16 : OUTS16(q) : "v"(rp1) : "memory");
        asm volatile(LOADS16 "s_waitcnt vmcnt(0)"
                     : OUTS16(r) : "v"(rp0) : "memory");
        __builtin_amdgcn_sched_barrier(0);
        ok = tag_ok16(q, tag1) & tag_ok16(r, tag0);
    } while (!ok);
    #pragma unroll
    for (int i = 0; i < 16; i++) {
        hd[32 * i] = __uint_as_float((q[i].x << 16) | (q[i].y & 0xFFFFu));
        ad[32 * i] = f2bf(__uint_as_float((r[i].x << 16) | (r[i].y & 0xFFFFu)));
    }
}

// ---------------- fused layer-pair scan (v12 = v9 structure + merged dual poll) -------
// 256 blocks x 512 threads: blocks 0..127 = layer0 (2 bgroups x 64 ublocks, 16 batches/
// group, 8 units/block); blocks 128..255 = layer1 (same partition).
// L1's input projection Wih1·h0(t): register-stationary bf16 MFMA; h0(t) staged bf16 in
// LDS [16][520]. Recurrent dots fp32 VALU. glds pointwise path + coalesced tid<128
// publish (v9-proven). L1 tail: poll_dual (one sweep for ring1 h1(t) + ring0 h0(t+1)).
__global__ __launch_bounds__(512) void scan_pair2(
    const float* __restrict__ gatesX0,  // [B*T][4H] layer0 x-proj incl bias
    const float* __restrict__ ctxAdd0,  // [B][4H] or null (decoder layer0)
    const float* __restrict__ Whh0,     // [4H][H]
    const float* __restrict__ Wih1,     // [4H][H] (-> register fragments, bf16)
    const float* __restrict__ Whh1,     // [4H][H]
    const float* __restrict__ b1,       // [4H]
    const float* __restrict__ h00, int sh00, const float* __restrict__ c00, int sc00,
    const float* __restrict__ h01, int sh01, const float* __restrict__ c01, int sc01,
    float* __restrict__ out0, float* __restrict__ out1,
    float* __restrict__ cT0o, float* __restrict__ cT1o,
    uint2* __restrict__ ring0, uint2* __restrict__ ring1,
    int tb0, int tb1)
{
    __shared__ float wlds[32 * 516];    // own-layer Whh slice (fp32)
    __shared__ float hmain[16 * 516];   // L0: h0(t-1); L1: h1(t-1)
    __shared__ float glds[16 * 36];     // h-dot results [batch][row]
    __shared__ ushort_t ah[16 * 520];   // L1: h0(t) bf16 (A-operand)
    __shared__ float pglds[8 * 256];    // L1: MFMA partials [kh*2+ni][batch*16+col]
    const int tid = threadIdx.x;
    const bool isL1 = blockIdx.x >= 128;
    const int rb = blockIdx.x & 127;
    const int bg = rb >> 6, ub = rb & 63, u0 = ub * 8;
    const int w = tid >> 6, l = tid & 63;
    const int bb = l >> 2, rr = w * 4 + (l & 3);       // dot role: batch 0..15, row 0..31
    const int grow = (rr >> 3) * HH + u0 + (rr & 7);
    const int batch = bg * 16 + bb;
    const int srow = tid >> 5, hc0 = tid & 31;         // staging role

    { // stationary own-layer Whh -> LDS
        const float* W = isL1 ? Whh1 : Whh0;
        const int sr = tid >> 4, ch = (tid & 15) * 32;
        const float* ws = W + (size_t)((sr >> 3) * HH + u0 + (sr & 7)) * HH + ch;
        float* wd = &wlds[sr * 516 + ch];
        #pragma unroll
        for (int j = 0; j < 32; j += 4) *(f32x4*)(wd + j) = *(const f32x4*)(ws + j);
    }
    // L1: stationary Wih1 bf16 B-fragments (r4/v9-verified layout). Wave (ni,kh):
    const int ni = w & 1, kh = w >> 1, lr = l & 15, ls = l >> 4;
    bf16x8 bfrag[4];
    if (isL1) {
        const int nrow = ni * 16 + lr;
        const int gN = (nrow >> 3) * HH + u0 + (nrow & 7);
        const float* wr = Wih1 + (size_t)gN * HH + kh * 128 + ls * 8;
        #pragma unroll
        for (int kk = 0; kk < 4; kk++) {
            float f[8];
            *(f32x4*)&f[0] = *(const f32x4*)(wr + kk * 32);
            *(f32x4*)&f[4] = *(const f32x4*)(wr + kk * 32 + 4);
            bf16x8 hv;
            #pragma unroll
            for (int j = 0; j < 8; j++) hv[j] = (short)f2bf(f[j]);
            bfrag[kk] = hv;
        }
    }
    { // initial own-recurrence h -> hmain (plain loads)
        const float* hsrc = isL1 ? h01 : h00;
        const int hstr = isL1 ? sh01 : sh00;
        const float* hs = hsrc + (size_t)(bg * 16 + srow) * hstr;
        float* hd = &hmain[srow * 516 + hc0];
        #pragma unroll
        for (int j = 0; j < 16; j++) hd[32 * j] = hs[hc0 + 32 * j];
    }
    // pointwise-thread state
    const int pb = tid >> 3, pu = tid & 7, gbatch = bg * 16 + pb;
    float creg = 0.f, b1v0 = 0.f, b1v1 = 0.f, b1v2 = 0.f, b1v3 = 0.f;
    if (tid < 128) {
        const float* ci = isL1 ? c01 : c00;
        const int cs = isL1 ? sc01 : sc00;
        creg = ci[(size_t)gbatch * cs + u0 + pu];
        if (isL1) {
            b1v0 = b1[0 * HH + u0 + pu]; b1v1 = b1[1 * HH + u0 + pu];
            b1v2 = b1[2 * HH + u0 + pu]; b1v3 = b1[3 * HH + u0 + pu];
        }
    }
    float xctx = 0.f, gx_cur = 0.f, gx_nxt = 0.f;
    const float* gxp = nullptr;
    if (!isL1) {
        gxp = gatesX0 + (size_t)batch * TT * G4H + grow;
        gx_cur = gxp[0];
        if (ctxAdd0) xctx = ctxAdd0[(size_t)batch * G4H + grow];
    } else {
        // h0(0) from L0's first publish
        const uint2* rp = ring0 + ((size_t)0 * BB + bg * 16 + srow) * HH + hc0;
        poll16_bf16(rp, (unsigned int)(tb0 + 1), &ah[srow * 520 + hc0]);
    }
    float* outp = isL1 ? out1 : out0;
    uint2* ringp = isL1 ? ring1 : ring0;
    const int tbase = isL1 ? tb1 : tb0;

    for (int t = 0; t < TT; ++t) {
        __syncthreads();   // staged inputs ready; prev glds consumed
        if (!isL1) {
            int tn = (t + 1 < TT) ? t + 1 : t;
            gx_nxt = gxp[(size_t)tn * G4H];
            f32x4 s = {0.f, 0.f, 0.f, 0.f};
            const float* hp = &hmain[bb * 516];
            const float* wp = &wlds[rr * 516];
            #pragma unroll 8
            for (int k = 0; k < HH; k += 4) {
                f32x4 hv = *(const f32x4*)(hp + k);
                f32x4 wv = *(const f32x4*)(wp + k);
                s.x = fmaf(hv.x, wv.x, s.x); s.y = fmaf(hv.y, wv.y, s.y);
                s.z = fmaf(hv.z, wv.z, s.z); s.w = fmaf(hv.w, wv.w, s.w);
            }
            glds[bb * 36 + rr] = gx_cur + xctx + ((s.x + s.y) + (s.z + s.w));
        } else {
            // x-projection: 4 MFMA (wave's K-span 128), A = h0(t) bf16, B = Wih1 frags
            f32x4 acc = {0.f, 0.f, 0.f, 0.f};
            const ushort_t* ab = &ah[lr * 520 + kh * 128 + ls * 8];
            #pragma unroll
            for (int kk = 0; kk < 4; kk++) {
                bf16x8 av = *(const bf16x8*)(ab + kk * 32);
                acc = __builtin_amdgcn_mfma_f32_16x16x32_bf16(av, bfrag[kk], acc, 0, 0, 0);
            }
            #pragma unroll
            for (int q = 0; q < 4; q++)
                pglds[(kh * 2 + ni) * 256 + (ls * 4 + q) * 16 + lr] = acc[q];
            // recurrent h-dot (fp32)
            f32x4 s = {0.f, 0.f, 0.f, 0.f};
            const float* hp = &hmain[bb * 516];
            const float* wp = &wlds[rr * 516];
            #pragma unroll 8
            for (int k = 0; k < HH; k += 4) {
                f32x4 hv = *(const f32x4*)(hp + k);
                f32x4 wv = *(const f32x4*)(wp + k);
                s.x = fmaf(hv.x, wv.x, s.x); s.y = fmaf(hv.y, wv.y, s.y);
                s.z = fmaf(hv.z, wv.z, s.z); s.w = fmaf(hv.w, wv.w, s.w);
            }
            glds[bb * 36 + rr] = (s.x + s.y) + (s.z + s.w);
        }
        __syncthreads();
        const unsigned int tag = (unsigned int)(tbase + t + 1);
        if (tid < 128) {
            float pre[4];
            if (!isL1) {
                #pragma unroll
                for (int g = 0; g < 4; g++) pre[g] = glds[pb * 36 + g * 8 + pu];
            } else {
                float bv[4] = {b1v0, b1v1, b1v2, b1v3};
                #pragma unroll
                for (int g = 0; g < 4; g++) {
                    int r = g * 8 + pu;
                    int nit = r >> 4, cr = r & 15;
                    float p = glds[pb * 36 + r] + bv[g];
                    #pragma unroll
                    for (int k2 = 0; k2 < 4; k2++)
                        p += pglds[(k2 * 2 + nit) * 256 + pb * 16 + cr];
                    pre[g] = p;
                }
            }
            float c = sigf(pre[1]) * creg + sigf(pre[0]) * tanh_(pre[2]);
            float h = sigf(pre[3]) * tanh_(c);
            creg = c;
            outp[((size_t)gbatch * TT + t) * HH + u0 + pu] = h;
            unsigned int hu = __float_as_uint(h);
            uint2 wv2;
            wv2.x = (tag << 16) | (hu >> 16);
            wv2.y = (tag << 16) | (hu & 0xFFFFu);
            uint2* pp = ringp + ((size_t)t * BB + gbatch) * HH + u0 + pu;
            asm volatile("global_store_dwordx2 %0, %1, off sc0 sc1"
                         :: "v"(pp), "v"(wv2) : "memory");
            if (t == TT - 1) {
                if (!isL1 && cT0o) cT0o[(size_t)gbatch * HH + u0 + pu] = c;
                if (isL1 && cT1o)  cT1o[(size_t)gbatch * HH + u0 + pu] = c;
            }
        }
        if (t + 1 < TT) {
            if (!isL1) {
                const uint2* rp = ring0 + ((size_t)t * BB + bg * 16 + srow) * HH + hc0;
                poll16_f32(rp, tag, &hmain[srow * 516 + hc0]);
            } else {
                const uint2* rp1 = ring1 + ((size_t)t * BB + bg * 16 + srow) * HH + hc0;
                const uint2* rp0 = ring0 + ((size_t)(t + 1) * BB + bg * 16 + srow) * HH + hc0;
                poll_dual(rp1, tag, &hmain[srow * 516 + hc0],
                          rp0, (unsigned int)(tb0 + t + 2), &ah[srow * 520 + hc0]);
            }
        }
        gx_cur = gx_nxt;
    }
}

// ---------------- final projection: bf16 MFMA GEMM, C = A*B^T + bias ----------------
__global__ __launch_bounds__(256) void gemm_bf16(
    const ushort_t* __restrict__ A,
    const float* __restrict__ B,
    const float* __restrict__ bias,
    float* __restrict__ C, int M, int N, int K)
{
    __shared__ ushort_t As[128 * 72];
    __shared__ ushort_t Bs[128 * 72];
    const int tid = threadIdx.x;
    const int bm = blockIdx.x * 128, bn = blockIdx.y * 128;
    const int lane = tid & 63, wave = tid >> 6;
    const int wm = (wave & 1) * 64, wn = (wave >> 1) * 64;
    const int lr = lane & 15, lk = (lane >> 4) * 8;
    const int srow = tid >> 3, sch = tid & 7;
    f32x4 acc[4][4] = {};

    for (int k0 = 0; k0 < K; k0 += 64) {
        #pragma unroll
        for (int rr = 0; rr < 4; rr++) {
            int row = srow + rr * 32;
            const ushort_t* as = A + (size_t)(bm + row) * K + k0 + sch * 8;
            *(int4*)&As[row * 72 + sch * 8] = *(const int4*)as;
            const float* bs = B + (size_t)(bn + row) * K + k0 + sch * 8;
            float4 f0 = *(const float4*)bs;
            float4 f1 = *(const float4*)(bs + 4);
            int4 pk;
            pk.x = (int)f2bf(f0.x) | ((int)f2bf(f0.y) << 16);
            pk.y = (int)f2bf(f0.z) | ((int)f2bf(f0.w) << 16);
            pk.z = (int)f2bf(f1.x) | ((int)f2bf(f1.y) << 16);
            pk.w = (int)f2bf(f1.z) | ((int)f2bf(f1.w) << 16);
            *(int4*)&Bs[row * 72 + sch * 8] = pk;
        }
        __syncthreads();
        #pragma unroll
        for (int k2 = 0; k2 < 64; k2 += 32) {
            bf16x8 a[4], bfr[4];
            #pragma unroll
            for (int i = 0; i < 4; i++)
                a[i] = *(const bf16x8*)&As[(wm + i * 16 + lr) * 72 + k2 + lk];
            #pragma unroll
            for (int j = 0; j < 4; j++)
                bfr[j] = *(const bf16x8*)&Bs[(wn + j * 16 + lr) * 72 + k2 + lk];
            #pragma unroll
            for (int i = 0; i < 4; i++)
                #pragma unroll
                for (int j = 0; j < 4; j++)
                    acc[i][j] = __builtin_amdgcn_mfma_f32_16x16x32_bf16(a[i], bfr[j], acc[i][j], 0, 0, 0);
        }
        __syncthreads();
    }
    const int r0 = (lane >> 4) * 4;
    #pragma unroll
    for (int j = 0; j < 4; j++) {
        int col = bn + wn + j * 16 + lr;
        float bv = bias[col];
        #pragma unroll
        for (int i = 0; i < 4; i++) {
            int row = bm + wm + i * 16 + r0;
            #pragma unroll
            for (int q = 0; q < 4; q++)
                C[(size_t)(row + q) * N + col] = acc[i][j][q] + bv;
        }
    }
}

extern "C" void kernel_launch(void* const* d_in, const int* in_sizes, int n_in,
                              void* d_out, int out_size, void* d_ws, size_t ws_size,
                              hipStream_t stream) {
    const int*   src      = (const int*)d_in[0];
    const int*   tgt      = (const int*)d_in[1];
    const float* enc_emb  = (const float*)d_in[2];
    const float* dec_emb  = (const float*)d_in[3];
    const float* eWih0    = (const float*)d_in[4];
    const float* eWhh0    = (const float*)d_in[5];
    const float* eb0      = (const float*)d_in[6];
    const float* eWih1    = (const float*)d_in[7];
    const float* eWhh1    = (const float*)d_in[8];
    const float* eb1      = (const float*)d_in[9];
    const float* dWih0    = (const float*)d_in[10];
    const float* dWhh0    = (const float*)d_in[11];
    const float* db0      = (const float*)d_in[12];
    const float* dWih1    = (const float*)d_in[13];
    const float* dWhh1    = (const float*)d_in[14];
    const float* db1      = (const float*)d_in[15];
    const float* pW1      = (const float*)d_in[16];
    const float* pb1      = (const float*)d_in[17];
    const float* pW2      = (const float*)d_in[18];
    const float* pb2      = (const float*)d_in[19];
    float* out = (float*)d_out;

    // workspace carve (small persistent buffers)
    float* fws   = (float*)d_ws;
    float* zeros = fws;                        // 512 f (padded to 1024)
    float* cT0   = fws + 2048;                 // 16384 f
    float* cT1   = cT0 + 16384;
    float* ctx   = cT1 + 16384;
    float* ctxW  = ctx + 16384;                // 65536 f
    ushort_t* hid = (ushort_t*)(ctxW + 65536); // 2048*512 bf16

    // d_out scratch (all dead before final projection writes everything)
    float* G0  = out;                 // 2048*2048 gate buffers
    float* G1  = G0 + 4194304;        // (unused; layout kept)
    float* G2  = G1 + 4194304;
    float* G3  = G2 + 4194304;        // (unused)
    float* xe  = G3 + 4194304;        // 2048*256
    float* xd  = xe + 524288;
    float* e0  = xd + 524288;         // 2048*512
    float* e1  = e0 + 1048576;
    float* d0  = e1 + 1048576;
    float* d1v = d0 + 1048576;
    uint2* ring0 = (uint2*)(d1v + 1048576);  // [64][32][512] tagged h (8 MB)
    uint2* ring1 = ring0 + 1048576;          // [64][32][512] tagged h (8 MB)

    zero_init<<<1, 256, 0, stream>>>(zeros);
    gather_rows<<<2048, 64, 0, stream>>>(src, enc_emb, xe);
    gather_rows<<<2048, 64, 0, stream>>>(tgt, dec_emb, xd);

    // layer-0 input projections (K=256, MFMA)
    gemm_mfma<<<dim3(16, 16), 256, 0, stream>>>(xe, 256, eWih0, 256, eb0, G0, 2048, 256, 0);
    gemm_mfma<<<dim3(16, 16), 256, 0, stream>>>(xd, 256, dWih0, 768, db0, G2, 2048, 256, 0);

    // fused encoder pair (enc0 + enc1 pipelined, skew 1)
    scan_pair2<<<256, 512, 0, stream>>>(
        G0, nullptr, eWhh0, eWih1, eWhh1, eb1,
        zeros, 0, zeros, 0, zeros, 0, zeros, 0,
        e0, e1, cT0, cT1, ring0, ring1, 0, 64);

    // context
    mean_ctx<<<64, 256, 0, stream>>>(e1, ctx);
    gemm_f32<<<dim3(32, 1), 256, 0, stream>>>(ctx, 512, dWih0 + 256, 768, nullptr, ctxW, 2048, 32, 2048, 512, 0);

    // fused decoder pair
    scan_pair2<<<256, 512, 0, stream>>>(
        G2, ctxW, dWhh0, dWih1, dWhh1, db1,
        e0 + 63 * 512, 64 * 512, cT0, 512,
        e1 + 63 * 512, 64 * 512, cT1, 512,
        d0, d1v, nullptr, nullptr, ring0, ring1, 128, 192);

    // projection: hid = tanh(d1*W1^T + b1) (MFMA, bf16 out); logits = hid*W2^T + b2
    gemm_mfma<<<dim3(16, 4), 256, 0, stream>>>(d1v, 512, pW1, 512, pb1, hid, 512, 512, 2);
    gemm_bf16<<<dim3(16, 250), 256, 0, stream>>>(hid, pW2, pb2, out, 2048, 32000, 512);
}

// Round 13
// 1673.376 us; speedup vs baseline: 1.1465x; 1.0378x over previous
//
#include <hip/hip_runtime.h>

typedef unsigned short ushort_t;
typedef __attribute__((ext_vector_type(8))) short bf16x8;
typedef __attribute__((ext_vector_type(4))) float f32x4;

#define BB 32
#define TT 64
#define HH 512
#define G4H 2048

__device__ __forceinline__ ushort_t f2bf(float f) {
    unsigned int u = __float_as_uint(f);
    unsigned int r = (u + 0x7fffu + ((u >> 16) & 1u)) >> 16;
    return (ushort_t)r;
}
__device__ __forceinline__ float sigf(float x) { return 1.f / (1.f + __expf(-x)); }
__device__ __forceinline__ float tanh_(float x) {
    float e = __expf(2.f * x);
    return 1.f - 2.f / (e + 1.f);
}

// ---------------- zero init (zeros vector for h0/c0) ----------------
__global__ void zero_init(float* zeros) {
    int t = threadIdx.x;
    if (t < 128) ((float4*)zeros)[t] = make_float4(0.f, 0.f, 0.f, 0.f); // 512 floats
}

// ---------------- embedding gather ----------------
__global__ void gather_rows(const int* __restrict__ idx, const float* __restrict__ emb,
                            float* __restrict__ out) {
    int row = blockIdx.x;      // 2048 rows
    int t = threadIdx.x;       // 64 threads
    int id = idx[row];
    float4 v = *(const float4*)(emb + (size_t)id * 256 + t * 4);
    *(float4*)(out + (size_t)row * 256 + t * 4) = v;
}

// ---------------- generic fp32 GEMM (tiny ctxW GEMM only) ----------------
__global__ __launch_bounds__(256) void gemm_f32(
    const float* __restrict__ A, int lda,
    const float* __restrict__ B, int ldb,
    const float* __restrict__ bias,
    void* __restrict__ Cv, int ldc,
    int M, int N, int K, int mode)
{
    __shared__ float As[16 * 68];
    __shared__ float Bs[16 * 68];
    const int tid = threadIdx.x;
    const int bm = blockIdx.y * 64, bn = blockIdx.x * 64;
    const int lr = tid >> 2, lk = (tid & 3) << 2;
    const int tr = (tid >> 4) << 2, tc = (tid & 15) << 2;
    float acc[4][4] = {};
    const int arow = bm + lr, brow = bn + lr;
    const bool aval = arow < M, bval = brow < N;
    const float* Ap = A + (size_t)arow * lda + lk;
    const float* Bp = B + (size_t)brow * ldb + lk;

    for (int k0 = 0; k0 < K; k0 += 16) {
        float4 av = make_float4(0.f, 0.f, 0.f, 0.f);
        float4 bv = make_float4(0.f, 0.f, 0.f, 0.f);
        if (aval) av = *(const float4*)(Ap + k0);
        if (bval) bv = *(const float4*)(Bp + k0);
        As[(lk + 0) * 68 + lr] = av.x; As[(lk + 1) * 68 + lr] = av.y;
        As[(lk + 2) * 68 + lr] = av.z; As[(lk + 3) * 68 + lr] = av.w;
        Bs[(lk + 0) * 68 + lr] = bv.x; Bs[(lk + 1) * 68 + lr] = bv.y;
        Bs[(lk + 2) * 68 + lr] = bv.z; Bs[(lk + 3) * 68 + lr] = bv.w;
        __syncthreads();
        #pragma unroll
        for (int kk = 0; kk < 16; kk++) {
            float4 a = *(const float4*)&As[kk * 68 + tr];
            float4 b = *(const float4*)&Bs[kk * 68 + tc];
            float ar[4] = {a.x, a.y, a.z, a.w};
            float br[4] = {b.x, b.y, b.z, b.w};
            #pragma unroll
            for (int i = 0; i < 4; i++)
                #pragma unroll
                for (int j = 0; j < 4; j++)
                    acc[i][j] = fmaf(ar[i], br[j], acc[i][j]);
        }
        __syncthreads();
    }
    #pragma unroll
    for (int i = 0; i < 4; i++) {
        int m = bm + tr + i;
        if (m >= M) continue;
        #pragma unroll
        for (int j = 0; j < 4; j++) {
            int n = bn + tc + j;
            if (n >= N) continue;
            float v = acc[i][j] + (bias ? bias[n] : 0.f);
            if (mode == 0) ((float*)Cv)[(size_t)m * ldc + n] = v;
            else ((ushort_t*)Cv)[(size_t)m * ldc + n] = f2bf(tanh_(v));
        }
    }
}

// ---------------- MFMA GEMM with f32->bf16 staging ----------------
__global__ __launch_bounds__(256) void gemm_mfma(
    const float* __restrict__ A, int lda,
    const float* __restrict__ B, int ldb,
    const float* __restrict__ bias,
    void* __restrict__ Cv, int ldc, int K, int mode)
{
    __shared__ ushort_t As[128 * 72];
    __shared__ ushort_t Bs[128 * 72];
    const int tid = threadIdx.x;
    const int bm = blockIdx.x * 128, bn = blockIdx.y * 128;
    const int lane = tid & 63, wave = tid >> 6;
    const int wm = (wave & 1) * 64, wn = (wave >> 1) * 64;
    const int lr = lane & 15, lk = (lane >> 4) * 8;
    const int srow = tid >> 3, sch = tid & 7;
    f32x4 acc[4][4] = {};

    for (int k0 = 0; k0 < K; k0 += 64) {
        #pragma unroll
        for (int rr = 0; rr < 4; rr++) {
            int row = srow + rr * 32;
            const float* as = A + (size_t)(bm + row) * lda + k0 + sch * 8;
            float4 a0 = *(const float4*)as;
            float4 a1 = *(const float4*)(as + 4);
            int4 pa;
            pa.x = (int)f2bf(a0.x) | ((int)f2bf(a0.y) << 16);
            pa.y = (int)f2bf(a0.z) | ((int)f2bf(a0.w) << 16);
            pa.z = (int)f2bf(a1.x) | ((int)f2bf(a1.y) << 16);
            pa.w = (int)f2bf(a1.z) | ((int)f2bf(a1.w) << 16);
            *(int4*)&As[row * 72 + sch * 8] = pa;
            const float* bs = B + (size_t)(bn + row) * ldb + k0 + sch * 8;
            float4 f0 = *(const float4*)bs;
            float4 f1 = *(const float4*)(bs + 4);
            int4 pk;
            pk.x = (int)f2bf(f0.x) | ((int)f2bf(f0.y) << 16);
            pk.y = (int)f2bf(f0.z) | ((int)f2bf(f0.w) << 16);
            pk.z = (int)f2bf(f1.x) | ((int)f2bf(f1.y) << 16);
            pk.w = (int)f2bf(f1.z) | ((int)f2bf(f1.w) << 16);
            *(int4*)&Bs[row * 72 + sch * 8] = pk;
        }
        __syncthreads();
        #pragma unroll
        for (int k2 = 0; k2 < 64; k2 += 32) {
            bf16x8 a[4], bfr[4];
            #pragma unroll
            for (int i = 0; i < 4; i++)
                a[i] = *(const bf16x8*)&As[(wm + i * 16 + lr) * 72 + k2 + lk];
            #pragma unroll
            for (int j = 0; j < 4; j++)
                bfr[j] = *(const bf16x8*)&Bs[(wn + j * 16 + lr) * 72 + k2 + lk];
            #pragma unroll
            for (int i = 0; i < 4; i++)
                #pragma unroll
                for (int j = 0; j < 4; j++)
                    acc[i][j] = __builtin_amdgcn_mfma_f32_16x16x32_bf16(a[i], bfr[j], acc[i][j], 0, 0, 0);
        }
        __syncthreads();
    }
    const int r0 = (lane >> 4) * 4;
    #pragma unroll
    for (int j = 0; j < 4; j++) {
        int col = bn + wn + j * 16 + lr;
        float bv = bias ? bias[col] : 0.f;
        #pragma unroll
        for (int i = 0; i < 4; i++) {
            int row = bm + wm + i * 16 + r0;
            #pragma unroll
            for (int q = 0; q < 4; q++) {
                float v = acc[i][j][q] + bv;
                if (mode == 0) ((float*)Cv)[(size_t)(row + q) * ldc + col] = v;
                else ((ushort_t*)Cv)[(size_t)(row + q) * ldc + col] = f2bf(tanh_(v));
            }
        }
    }
}

// ---------------- context mean ----------------
__global__ void mean_ctx(const float* __restrict__ e1, float* __restrict__ ctx) {
    int g = blockIdx.x * 256 + threadIdx.x; // 16384
    int b = g >> 9, u = g & 511;
    float s = 0.f;
    #pragma unroll 8
    for (int t = 0; t < TT; t++) s += e1[((size_t)b * TT + t) * HH + u];
    ctx[g] = s * (1.f / 64.f);
}

// ---- tagged poll primitives (v6-verified protocol) ----
#define LOADS16                                                            \
        "global_load_dwordx2 %0, %16, off sc0 sc1\n\t"                     \
        "global_load_dwordx2 %1, %16, off offset:256 sc0 sc1\n\t"          \
        "global_load_dwordx2 %2, %16, off offset:512 sc0 sc1\n\t"          \
        "global_load_dwordx2 %3, %16, off offset:768 sc0 sc1\n\t"          \
        "global_load_dwordx2 %4, %16, off offset:1024 sc0 sc1\n\t"         \
        "global_load_dwordx2 %5, %16, off offset:1280 sc0 sc1\n\t"         \
        "global_load_dwordx2 %6, %16, off offset:1536 sc0 sc1\n\t"         \
        "global_load_dwordx2 %7, %16, off offset:1792 sc0 sc1\n\t"         \
        "global_load_dwordx2 %8, %16, off offset:2048 sc0 sc1\n\t"         \
        "global_load_dwordx2 %9, %16, off offset:2304 sc0 sc1\n\t"         \
        "global_load_dwordx2 %10, %16, off offset:2560 sc0 sc1\n\t"        \
        "global_load_dwordx2 %11, %16, off offset:2816 sc0 sc1\n\t"        \
        "global_load_dwordx2 %12, %16, off offset:3072 sc0 sc1\n\t"        \
        "global_load_dwordx2 %13, %16, off offset:3328 sc0 sc1\n\t"        \
        "global_load_dwordx2 %14, %16, off offset:3584 sc0 sc1\n\t"        \
        "global_load_dwordx2 %15, %16, off offset:3840 sc0 sc1\n\t"

#define OUTS16(a) "=&v"(a[0]), "=&v"(a[1]), "=&v"(a[2]), "=&v"(a[3]),      \
                  "=&v"(a[4]), "=&v"(a[5]), "=&v"(a[6]), "=&v"(a[7]),      \
                  "=&v"(a[8]), "=&v"(a[9]), "=&v"(a[10]), "=&v"(a[11]),    \
                  "=&v"(a[12]), "=&v"(a[13]), "=&v"(a[14]), "=&v"(a[15])

__device__ __forceinline__ bool tag_ok16(const uint2* q, unsigned int tag) {
    unsigned int a = 0xFFFFFFFFu, o = 0u;
    #pragma unroll
    for (int i = 0; i < 16; i++) { a &= q[i].x & q[i].y; o |= q[i].x | q[i].y; }
    return ((a >> 16) == tag) & ((o >> 16) == tag);
}

__device__ __forceinline__ void poll16_f32(const uint2* rp, unsigned int tag, float* hd) {
    uint2 q[16];
    bool ok;
    do {
        asm volatile(LOADS16 "s_waitcnt vmcnt(0)"
                     : OUTS16(q) : "v"(rp) : "memory");
        __builtin_amdgcn_sched_barrier(0);
        ok = tag_ok16(q, tag);
    } while (!ok);
    #pragma unroll
    for (int i = 0; i < 16; i++)
        hd[32 * i] = __uint_as_float((q[i].x << 16) | (q[i].y & 0xFFFFu));
}
__device__ __forceinline__ void poll16_bf16(const uint2* rp, unsigned int tag, ushort_t* hd) {
    uint2 q[16];
    bool ok;
    do {
        asm volatile(LOADS16 "s_waitcnt vmcnt(0)"
                     : OUTS16(q) : "v"(rp) : "memory");
        __builtin_amdgcn_sched_barrier(0);
        ok = tag_ok16(q, tag);
    } while (!ok);
    #pragma unroll
    for (int i = 0; i < 16; i++)
        hd[32 * i] = f2bf(__uint_as_float((q[i].x << 16) | (q[i].y & 0xFFFFu)));
}
// two-row single-ring spin (32 loads, one waitcnt) — used by the split-wave L1 tail
__device__ __forceinline__ void poll2_f32(const uint2* rpA, const uint2* rpB,
                                          unsigned int tag, float* hdA, float* hdB) {
    uint2 q[16], r[16];
    bool ok;
    do {
        asm volatile(LOADS16 : OUTS16(q) : "v"(rpA) : "memory");
        asm volatile(LOADS16 "s_waitcnt vmcnt(0)"
                     : OUTS16(r) : "v"(rpB) : "memory");
        __builtin_amdgcn_sched_barrier(0);
        ok = tag_ok16(q, tag) & tag_ok16(r, tag);
    } while (!ok);
    #pragma unroll
    for (int i = 0; i < 16; i++) {
        hdA[32 * i] = __uint_as_float((q[i].x << 16) | (q[i].y & 0xFFFFu));
        hdB[32 * i] = __uint_as_float((r[i].x << 16) | (r[i].y & 0xFFFFu));
    }
}
__device__ __forceinline__ void poll2_bf16(const uint2* rpA, const uint2* rpB,
                                           unsigned int tag, ushort_t* hdA, ushort_t* hdB) {
    uint2 q[16], r[16];
    bool ok;
    do {
        asm volatile(LOADS16 : OUTS16(q) : "v"(rpA) : "memory");
        asm volatile(LOADS16 "s_waitcnt vmcnt(0)"
                     : OUTS16(r) : "v"(rpB) : "memory");
        __builtin_amdgcn_sched_barrier(0);
        ok = tag_ok16(q, tag) & tag_ok16(r, tag);
    } while (!ok);
    #pragma unroll
    for (int i = 0; i < 16; i++) {
        hdA[32 * i] = f2bf(__uint_as_float((q[i].x << 16) | (q[i].y & 0xFFFFu)));
        hdB[32 * i] = f2bf(__uint_as_float((r[i].x << 16) | (r[i].y & 0xFFFFu)));
    }
}

// ---------------- fused layer-pair scan (v13 = v9 + split-wave L1 tail polls) ---------
// 256 blocks x 512 threads: blocks 0..127 = layer0, 128..255 = layer1 (2 bgroups x 64
// ublocks; 16 batches/group; 8 units/block). L1 x-proj: register-stationary bf16 MFMA.
// Recurrent dots fp32 VALU. Coalesced tid<128 publish + glds pointwise (v9-proven).
// L1 tail: waves 0-3 spin on ring1(t)->hmain while waves 4-7 spin on ring0(t+1)->ah
// CONCURRENTLY -> tail cost = max(sweepA, sweepB) instead of sum (r12's merged-spin
// mistake avoided: each spin is a single-ring 32-load sweep over its own data).
__global__ __launch_bounds__(512) void scan_pair2(
    const float* __restrict__ gatesX0,  // [B*T][4H] layer0 x-proj incl bias
    const float* __restrict__ ctxAdd0,  // [B][4H] or null (decoder layer0)
    const float* __restrict__ Whh0,     // [4H][H]
    const float* __restrict__ Wih1,     // [4H][H] (-> register fragments, bf16)
    const float* __restrict__ Whh1,     // [4H][H]
    const float* __restrict__ b1,       // [4H]
    const float* __restrict__ h00, int sh00, const float* __restrict__ c00, int sc00,
    const float* __restrict__ h01, int sh01, const float* __restrict__ c01, int sc01,
    float* __restrict__ out0, float* __restrict__ out1,
    float* __restrict__ cT0o, float* __restrict__ cT1o,
    uint2* __restrict__ ring0, uint2* __restrict__ ring1,
    int tb0, int tb1)
{
    __shared__ float wlds[32 * 516];    // own-layer Whh slice (fp32)
    __shared__ float hmain[16 * 516];   // L0: h0(t-1); L1: h1(t-1)
    __shared__ float glds[16 * 36];     // h-dot results [batch][row]
    __shared__ ushort_t ah[16 * 520];   // L1: h0(t) bf16 (A-operand)
    __shared__ float pglds[8 * 256];    // L1: MFMA partials [kh*2+ni][batch*16+col]
    const int tid = threadIdx.x;
    const bool isL1 = blockIdx.x >= 128;
    const int rb = blockIdx.x & 127;
    const int bg = rb >> 6, ub = rb & 63, u0 = ub * 8;
    const int w = tid >> 6, l = tid & 63;
    const int bb = l >> 2, rr = w * 4 + (l & 3);       // dot role: batch 0..15, row 0..31
    const int grow = (rr >> 3) * HH + u0 + (rr & 7);
    const int batch = bg * 16 + bb;
    const int srow = tid >> 5, hc0 = tid & 31;         // staging role (full-block polls)

    { // stationary own-layer Whh -> LDS
        const float* W = isL1 ? Whh1 : Whh0;
        const int sr = tid >> 4, ch = (tid & 15) * 32;
        const float* ws = W + (size_t)((sr >> 3) * HH + u0 + (sr & 7)) * HH + ch;
        float* wd = &wlds[sr * 516 + ch];
        #pragma unroll
        for (int j = 0; j < 32; j += 4) *(f32x4*)(wd + j) = *(const f32x4*)(ws + j);
    }
    // L1: stationary Wih1 bf16 B-fragments (r4/v9-verified layout). Wave (ni,kh):
    const int ni = w & 1, kh = w >> 1, lr = l & 15, ls = l >> 4;
    bf16x8 bfrag[4];
    if (isL1) {
        const int nrow = ni * 16 + lr;
        const int gN = (nrow >> 3) * HH + u0 + (nrow & 7);
        const float* wr = Wih1 + (size_t)gN * HH + kh * 128 + ls * 8;
        #pragma unroll
        for (int kk = 0; kk < 4; kk++) {
            float f[8];
            *(f32x4*)&f[0] = *(const f32x4*)(wr + kk * 32);
            *(f32x4*)&f[4] = *(const f32x4*)(wr + kk * 32 + 4);
            bf16x8 hv;
            #pragma unroll
            for (int j = 0; j < 8; j++) hv[j] = (short)f2bf(f[j]);
            bfrag[kk] = hv;
        }
    }
    { // initial own-recurrence h -> hmain (plain loads)
        const float* hsrc = isL1 ? h01 : h00;
        const int hstr = isL1 ? sh01 : sh00;
        const float* hs = hsrc + (size_t)(bg * 16 + srow) * hstr;
        float* hd = &hmain[srow * 516 + hc0];
        #pragma unroll
        for (int j = 0; j < 16; j++) hd[32 * j] = hs[hc0 + 32 * j];
    }
    // pointwise-thread state
    const int pb = tid >> 3, pu = tid & 7, gbatch = bg * 16 + pb;
    float creg = 0.f, b1v0 = 0.f, b1v1 = 0.f, b1v2 = 0.f, b1v3 = 0.f;
    if (tid < 128) {
        const float* ci = isL1 ? c01 : c00;
        const int cs = isL1 ? sc01 : sc00;
        creg = ci[(size_t)gbatch * cs + u0 + pu];
        if (isL1) {
            b1v0 = b1[0 * HH + u0 + pu]; b1v1 = b1[1 * HH + u0 + pu];
            b1v2 = b1[2 * HH + u0 + pu]; b1v3 = b1[3 * HH + u0 + pu];
        }
    }
    float xctx = 0.f, gx_cur = 0.f, gx_nxt = 0.f;
    const float* gxp = nullptr;
    if (!isL1) {
        gxp = gatesX0 + (size_t)batch * TT * G4H + grow;
        gx_cur = gxp[0];
        if (ctxAdd0) xctx = ctxAdd0[(size_t)batch * G4H + grow];
    } else {
        // h0(0) from L0's first publish (full-block poll)
        const uint2* rp = ring0 + ((size_t)0 * BB + bg * 16 + srow) * HH + hc0;
        poll16_bf16(rp, (unsigned int)(tb0 + 1), &ah[srow * 520 + hc0]);
    }
    float* outp = isL1 ? out1 : out0;
    uint2* ringp = isL1 ? ring1 : ring0;
    const int tbase = isL1 ? tb1 : tb0;

    for (int t = 0; t < TT; ++t) {
        __syncthreads();   // staged inputs ready; prev glds consumed
        if (!isL1) {
            int tn = (t + 1 < TT) ? t + 1 : t;
            gx_nxt = gxp[(size_t)tn * G4H];
            f32x4 s = {0.f, 0.f, 0.f, 0.f};
            const float* hp = &hmain[bb * 516];
            const float* wp = &wlds[rr * 516];
            #pragma unroll 8
            for (int k = 0; k < HH; k += 4) {
                f32x4 hv = *(const f32x4*)(hp + k);
                f32x4 wv = *(const f32x4*)(wp + k);
                s.x = fmaf(hv.x, wv.x, s.x); s.y = fmaf(hv.y, wv.y, s.y);
                s.z = fmaf(hv.z, wv.z, s.z); s.w = fmaf(hv.w, wv.w, s.w);
            }
            glds[bb * 36 + rr] = gx_cur + xctx + ((s.x + s.y) + (s.z + s.w));
        } else {
            // x-projection: 4 MFMA (wave's K-span 128), A = h0(t) bf16, B = Wih1 frags
            f32x4 acc = {0.f, 0.f, 0.f, 0.f};
            const ushort_t* ab = &ah[lr * 520 + kh * 128 + ls * 8];
            #pragma unroll
            for (int kk = 0; kk < 4; kk++) {
                bf16x8 av = *(const bf16x8*)(ab + kk * 32);
                acc = __builtin_amdgcn_mfma_f32_16x16x32_bf16(av, bfrag[kk], acc, 0, 0, 0);
            }
            #pragma unroll
            for (int q = 0; q < 4; q++)
                pglds[(kh * 2 + ni) * 256 + (ls * 4 + q) * 16 + lr] = acc[q];
            // recurrent h-dot (fp32)
            f32x4 s = {0.f, 0.f, 0.f, 0.f};
            const float* hp = &hmain[bb * 516];
            const float* wp = &wlds[rr * 516];
            #pragma unroll 8
            for (int k = 0; k < HH; k += 4) {
                f32x4 hv = *(const f32x4*)(hp + k);
                f32x4 wv = *(const f32x4*)(wp + k);
                s.x = fmaf(hv.x, wv.x, s.x); s.y = fmaf(hv.y, wv.y, s.y);
                s.z = fmaf(hv.z, wv.z, s.z); s.w = fmaf(hv.w, wv.w, s.w);
            }
            glds[bb * 36 + rr] = (s.x + s.y) + (s.z + s.w);
        }
        __syncthreads();
        const unsigned int tag = (unsigned int)(tbase + t + 1);
        if (tid < 128) {
            float pre[4];
            if (!isL1) {
                #pragma unroll
                for (int g = 0; g < 4; g++) pre[g] = glds[pb * 36 + g * 8 + pu];
            } else {
                float bv[4] = {b1v0, b1v1, b1v2, b1v3};
                #pragma unroll
                for (int g = 0; g < 4; g++) {
                    int r = g * 8 + pu;
                    int nit = r >> 4, cr = r & 15;
                    float p = glds[pb * 36 + r] + bv[g];
                    #pragma unroll
                    for (int k2 = 0; k2 < 4; k2++)
                        p += pglds[(k2 * 2 + nit) * 256 + pb * 16 + cr];
                    pre[g] = p;
                }
            }
            float c = sigf(pre[1]) * creg + sigf(pre[0]) * tanh_(pre[2]);
            float h = sigf(pre[3]) * tanh_(c);
            creg = c;
            outp[((size_t)gbatch * TT + t) * HH + u0 + pu] = h;
            unsigned int hu = __float_as_uint(h);
            uint2 wv2;
            wv2.x = (tag << 16) | (hu >> 16);
            wv2.y = (tag << 16) | (hu & 0xFFFFu);
            uint2* pp = ringp + ((size_t)t * BB + gbatch) * HH + u0 + pu;
            asm volatile("global_store_dwordx2 %0, %1, off sc0 sc1"
                         :: "v"(pp), "v"(wv2) : "memory");
            if (t == TT - 1) {
                if (!isL1 && cT0o) cT0o[(size_t)gbatch * HH + u0 + pu] = c;
                if (isL1 && cT1o)  cT1o[(size_t)gbatch * HH + u0 + pu] = c;
            }
        }
        if (t + 1 < TT) {
            if (!isL1) {
                const uint2* rp = ring0 + ((size_t)t * BB + bg * 16 + srow) * HH + hc0;
                poll16_f32(rp, tag, &hmain[srow * 516 + hc0]);
            } else {
                // split-wave: lower half handles ring1(t)->hmain (2 rows/thread),
                // upper half handles ring0(t+1)->ah (2 rows/thread) CONCURRENTLY
                const int hh = tid & 255;
                const int ra = hh >> 5, rb2 = ra + 8, hcc = hh & 31;
                if (tid < 256) {
                    const uint2* rpA = ring1 + ((size_t)t * BB + bg * 16 + ra) * HH + hcc;
                    const uint2* rpB = ring1 + ((size_t)t * BB + bg * 16 + rb2) * HH + hcc;
                    poll2_f32(rpA, rpB, tag,
                              &hmain[ra * 516 + hcc], &hmain[rb2 * 516 + hcc]);
                } else {
                    const unsigned int tg0 = (unsigned int)(tb0 + t + 2);
                    const uint2* rpA = ring0 + ((size_t)(t + 1) * BB + bg * 16 + ra) * HH + hcc;
                    const uint2* rpB = ring0 + ((size_t)(t + 1) * BB + bg * 16 + rb2) * HH + hcc;
                    poll2_bf16(rpA, rpB, tg0,
                               &ah[ra * 520 + hcc], &ah[rb2 * 520 + hcc]);
                }
            }
        }
        gx_cur = gx_nxt;
    }
}

// ---------------- final projection: bf16 MFMA GEMM, C = A*B^T + bias ----------------
__global__ __launch_bounds__(256) void gemm_bf16(
    const ushort_t* __restrict__ A,
    const float* __restrict__ B,
    const float* __restrict__ bias,
    float* __restrict__ C, int M, int N, int K)
{
    __shared__ ushort_t As[128 * 72];
    __shared__ ushort_t Bs[128 * 72];
    const int tid = threadIdx.x;
    const int bm = blockIdx.x * 128, bn = blockIdx.y * 128;
    const int lane = tid & 63, wave = tid >> 6;
    const int wm = (wave & 1) * 64, wn = (wave >> 1) * 64;
    const int lr = lane & 15, lk = (lane >> 4) * 8;
    const int srow = tid >> 3, sch = tid & 7;
    f32x4 acc[4][4] = {};

    for (int k0 = 0; k0 < K; k0 += 64) {
        #pragma unroll
        for (int rr = 0; rr < 4; rr++) {
            int row = srow + rr * 32;
            const ushort_t* as = A + (size_t)(bm + row) * K + k0 + sch * 8;
            *(int4*)&As[row * 72 + sch * 8] = *(const int4*)as;
            const float* bs = B + (size_t)(bn + row) * K + k0 + sch * 8;
            float4 f0 = *(const float4*)bs;
            float4 f1 = *(const float4*)(bs + 4);
            int4 pk;
            pk.x = (int)f2bf(f0.x) | ((int)f2bf(f0.y) << 16);
            pk.y = (int)f2bf(f0.z) | ((int)f2bf(f0.w) << 16);
            pk.z = (int)f2bf(f1.x) | ((int)f2bf(f1.y) << 16);
            pk.w = (int)f2bf(f1.z) | ((int)f2bf(f1.w) << 16);
            *(int4*)&Bs[row * 72 + sch * 8] = pk;
        }
        __syncthreads();
        #pragma unroll
        for (int k2 = 0; k2 < 64; k2 += 32) {
            bf16x8 a[4], bfr[4];
            #pragma unroll
            for (int i = 0; i < 4; i++)
                a[i] = *(const bf16x8*)&As[(wm + i * 16 + lr) * 72 + k2 + lk];
            #pragma unroll
            for (int j = 0; j < 4; j++)
                bfr[j] = *(const bf16x8*)&Bs[(wn + j * 16 + lr) * 72 + k2 + lk];
            #pragma unroll
            for (int i = 0; i < 4; i++)
                #pragma unroll
                for (int j = 0; j < 4; j++)
                    acc[i][j] = __builtin_amdgcn_mfma_f32_16x16x32_bf16(a[i], bfr[j], acc[i][j], 0, 0, 0);
        }
        __syncthreads();
    }
    const int r0 = (lane >> 4) * 4;
    #pragma unroll
    for (int j = 0; j < 4; j++) {
        int col = bn + wn + j * 16 + lr;
        float bv = bias[col];
        #pragma unroll
        for (int i = 0; i < 4; i++) {
            int row = bm + wm + i * 16 + r0;
            #pragma unroll
            for (int q = 0; q < 4; q++)
                C[(size_t)(row + q) * N + col] = acc[i][j][q] + bv;
        }
    }
}

extern "C" void kernel_launch(void* const* d_in, const int* in_sizes, int n_in,
                              void* d_out, int out_size, void* d_ws, size_t ws_size,
                              hipStream_t stream) {
    const int*   src      = (const int*)d_in[0];
    const int*   tgt      = (const int*)d_in[1];
    const float* enc_emb  = (const float*)d_in[2];
    const float* dec_emb  = (const float*)d_in[3];
    const float* eWih0    = (const float*)d_in[4];
    const float* eWhh0    = (const float*)d_in[5];
    const float* eb0      = (const float*)d_in[6];
    const float* eWih1    = (const float*)d_in[7];
    const float* eWhh1    = (const float*)d_in[8];
    const float* eb1      = (const float*)d_in[9];
    const float* dWih0    = (const float*)d_in[10];
    const float* dWhh0    = (const float*)d_in[11];
    const float* db0      = (const float*)d_in[12];
    const float* dWih1    = (const float*)d_in[13];
    const float* dWhh1    = (const float*)d_in[14];
    const float* db1      = (const float*)d_in[15];
    const float* pW1      = (const float*)d_in[16];
    const float* pb1      = (const float*)d_in[17];
    const float* pW2      = (const float*)d_in[18];
    const float* pb2      = (const float*)d_in[19];
    float* out = (float*)d_out;

    // workspace carve (small persistent buffers)
    float* fws   = (float*)d_ws;
    float* zeros = fws;                        // 512 f (padded to 1024)
    float* cT0   = fws + 2048;                 // 16384 f
    float* cT1   = cT0 + 16384;
    float* ctx   = cT1 + 16384;
    float* ctxW  = ctx + 16384;                // 65536 f
    ushort_t* hid = (ushort_t*)(ctxW + 65536); // 2048*512 bf16

    // d_out scratch (all dead before final projection writes everything)
    float* G0  = out;                 // 2048*2048 gate buffers
    float* G1  = G0 + 4194304;        // (unused; layout kept)
    float* G2  = G1 + 4194304;
    float* G3  = G2 + 4194304;        // (unused)
    float* xe  = G3 + 4194304;        // 2048*256
    float* xd  = xe + 524288;
    float* e0  = xd + 524288;         // 2048*512
    float* e1  = e0 + 1048576;
    float* d0  = e1 + 1048576;
    float* d1v = d0 + 1048576;
    uint2* ring0 = (uint2*)(d1v + 1048576);  // [64][32][512] tagged h (8 MB)
    uint2* ring1 = ring0 + 1048576;          // [64][32][512] tagged h (8 MB)

    zero_init<<<1, 256, 0, stream>>>(zeros);
    gather_rows<<<2048, 64, 0, stream>>>(src, enc_emb, xe);
    gather_rows<<<2048, 64, 0, stream>>>(tgt, dec_emb, xd);

    // layer-0 input projections (K=256, MFMA)
    gemm_mfma<<<dim3(16, 16), 256, 0, stream>>>(xe, 256, eWih0, 256, eb0, G0, 2048, 256, 0);
    gemm_mfma<<<dim3(16, 16), 256, 0, stream>>>(xd, 256, dWih0, 768, db0, G2, 2048, 256, 0);

    // fused encoder pair (enc0 + enc1 pipelined, skew 1)
    scan_pair2<<<256, 512, 0, stream>>>(
        G0, nullptr, eWhh0, eWih1, eWhh1, eb1,
        zeros, 0, zeros, 0, zeros, 0, zeros, 0,
        e0, e1, cT0, cT1, ring0, ring1, 0, 64);

    // context
    mean_ctx<<<64, 256, 0, stream>>>(e1, ctx);
    gemm_f32<<<dim3(32, 1), 256, 0, stream>>>(ctx, 512, dWih0 + 256, 768, nullptr, ctxW, 2048, 32, 2048, 512, 0);

    // fused decoder pair
    scan_pair2<<<256, 512, 0, stream>>>(
        G2, ctxW, dWhh0, dWih1, dWhh1, db1,
        e0 + 63 * 512, 64 * 512, cT0, 512,
        e1 + 63 * 512, 64 * 512, cT1, 512,
        d0, d1v, nullptr, nullptr, ring0, ring1, 128, 192);

    // projection: hid = tanh(d1*W1^T + b1) (MFMA, bf16 out); logits = hid*W2^T + b2
    gemm_mfma<<<dim3(16, 4), 256, 0, stream>>>(d1v, 512, pW1, 512, pb1, hid, 512, 512, 2);
    gemm_bf16<<<dim3(16, 250), 256, 0, stream>>>(hid, pW2, pb2, out, 2048, 32000, 512);
}

// Round 14
// 1442.878 us; speedup vs baseline: 1.3297x; 1.1597x over previous
//
#include <hip/hip_runtime.h>

typedef unsigned short ushort_t;
typedef __attribute__((ext_vector_type(8))) short bf16x8;
typedef __attribute__((ext_vector_type(4))) float f32x4;

#define BB 32
#define TT 64
#define HH 512
#define G4H 2048

__device__ __forceinline__ ushort_t f2bf(float f) {
    unsigned int u = __float_as_uint(f);
    unsigned int r = (u + 0x7fffu + ((u >> 16) & 1u)) >> 16;
    return (ushort_t)r;
}
__device__ __forceinline__ void split_bf(float f, ushort_t& hi, ushort_t& lo) {
    unsigned int hu = f2bf(f);
    hi = (ushort_t)hu;
    float hf = __uint_as_float((unsigned int)hu << 16);
    lo = f2bf(f - hf);
}
__device__ __forceinline__ float sigf(float x) { return 1.f / (1.f + __expf(-x)); }
__device__ __forceinline__ float tanh_(float x) {
    float e = __expf(2.f * x);
    return 1.f - 2.f / (e + 1.f);
}

// ---------------- zero init (zeros vector for h0/c0) ----------------
__global__ void zero_init(float* zeros) {
    int t = threadIdx.x;
    if (t < 128) ((float4*)zeros)[t] = make_float4(0.f, 0.f, 0.f, 0.f); // 512 floats
}

// ---------------- embedding gather ----------------
__global__ void gather_rows(const int* __restrict__ idx, const float* __restrict__ emb,
                            float* __restrict__ out) {
    int row = blockIdx.x;      // 2048 rows
    int t = threadIdx.x;       // 64 threads
    int id = idx[row];
    float4 v = *(const float4*)(emb + (size_t)id * 256 + t * 4);
    *(float4*)(out + (size_t)row * 256 + t * 4) = v;
}

// ---------------- generic fp32 GEMM (tiny ctxW GEMM only) ----------------
__global__ __launch_bounds__(256) void gemm_f32(
    const float* __restrict__ A, int lda,
    const float* __restrict__ B, int ldb,
    const float* __restrict__ bias,
    void* __restrict__ Cv, int ldc,
    int M, int N, int K, int mode)
{
    __shared__ float As[16 * 68];
    __shared__ float Bs[16 * 68];
    const int tid = threadIdx.x;
    const int bm = blockIdx.y * 64, bn = blockIdx.x * 64;
    const int lr = tid >> 2, lk = (tid & 3) << 2;
    const int tr = (tid >> 4) << 2, tc = (tid & 15) << 2;
    float acc[4][4] = {};
    const int arow = bm + lr, brow = bn + lr;
    const bool aval = arow < M, bval = brow < N;
    const float* Ap = A + (size_t)arow * lda + lk;
    const float* Bp = B + (size_t)brow * ldb + lk;

    for (int k0 = 0; k0 < K; k0 += 16) {
        float4 av = make_float4(0.f, 0.f, 0.f, 0.f);
        float4 bv = make_float4(0.f, 0.f, 0.f, 0.f);
        if (aval) av = *(const float4*)(Ap + k0);
        if (bval) bv = *(const float4*)(Bp + k0);
        As[(lk + 0) * 68 + lr] = av.x; As[(lk + 1) * 68 + lr] = av.y;
        As[(lk + 2) * 68 + lr] = av.z; As[(lk + 3) * 68 + lr] = av.w;
        Bs[(lk + 0) * 68 + lr] = bv.x; Bs[(lk + 1) * 68 + lr] = bv.y;
        Bs[(lk + 2) * 68 + lr] = bv.z; Bs[(lk + 3) * 68 + lr] = bv.w;
        __syncthreads();
        #pragma unroll
        for (int kk = 0; kk < 16; kk++) {
            float4 a = *(const float4*)&As[kk * 68 + tr];
            float4 b = *(const float4*)&Bs[kk * 68 + tc];
            float ar[4] = {a.x, a.y, a.z, a.w};
            float br[4] = {b.x, b.y, b.z, b.w};
            #pragma unroll
            for (int i = 0; i < 4; i++)
                #pragma unroll
                for (int j = 0; j < 4; j++)
                    acc[i][j] = fmaf(ar[i], br[j], acc[i][j]);
        }
        __syncthreads();
    }
    #pragma unroll
    for (int i = 0; i < 4; i++) {
        int m = bm + tr + i;
        if (m >= M) continue;
        #pragma unroll
        for (int j = 0; j < 4; j++) {
            int n = bn + tc + j;
            if (n >= N) continue;
            float v = acc[i][j] + (bias ? bias[n] : 0.f);
            if (mode == 0) ((float*)Cv)[(size_t)m * ldc + n] = v;
            else ((ushort_t*)Cv)[(size_t)m * ldc + n] = f2bf(tanh_(v));
        }
    }
}

// ---------------- MFMA GEMM with f32->bf16 staging ----------------
__global__ __launch_bounds__(256) void gemm_mfma(
    const float* __restrict__ A, int lda,
    const float* __restrict__ B, int ldb,
    const float* __restrict__ bias,
    void* __restrict__ Cv, int ldc, int K, int mode)
{
    __shared__ ushort_t As[128 * 72];
    __shared__ ushort_t Bs[128 * 72];
    const int tid = threadIdx.x;
    const int bm = blockIdx.x * 128, bn = blockIdx.y * 128;
    const int lane = tid & 63, wave = tid >> 6;
    const int wm = (wave & 1) * 64, wn = (wave >> 1) * 64;
    const int lr = lane & 15, lk = (lane >> 4) * 8;
    const int srow = tid >> 3, sch = tid & 7;
    f32x4 acc[4][4] = {};

    for (int k0 = 0; k0 < K; k0 += 64) {
        #pragma unroll
        for (int rr = 0; rr < 4; rr++) {
            int row = srow + rr * 32;
            const float* as = A + (size_t)(bm + row) * lda + k0 + sch * 8;
            float4 a0 = *(const float4*)as;
            float4 a1 = *(const float4*)(as + 4);
            int4 pa;
            pa.x = (int)f2bf(a0.x) | ((int)f2bf(a0.y) << 16);
            pa.y = (int)f2bf(a0.z) | ((int)f2bf(a0.w) << 16);
            pa.z = (int)f2bf(a1.x) | ((int)f2bf(a1.y) << 16);
            pa.w = (int)f2bf(a1.z) | ((int)f2bf(a1.w) << 16);
            *(int4*)&As[row * 72 + sch * 8] = pa;
            const float* bs = B + (size_t)(bn + row) * ldb + k0 + sch * 8;
            float4 f0 = *(const float4*)bs;
            float4 f1 = *(const float4*)(bs + 4);
            int4 pk;
            pk.x = (int)f2bf(f0.x) | ((int)f2bf(f0.y) << 16);
            pk.y = (int)f2bf(f0.z) | ((int)f2bf(f0.w) << 16);
            pk.z = (int)f2bf(f1.x) | ((int)f2bf(f1.y) << 16);
            pk.w = (int)f2bf(f1.z) | ((int)f2bf(f1.w) << 16);
            *(int4*)&Bs[row * 72 + sch * 8] = pk;
        }
        __syncthreads();
        #pragma unroll
        for (int k2 = 0; k2 < 64; k2 += 32) {
            bf16x8 a[4], bfr[4];
            #pragma unroll
            for (int i = 0; i < 4; i++)
                a[i] = *(const bf16x8*)&As[(wm + i * 16 + lr) * 72 + k2 + lk];
            #pragma unroll
            for (int j = 0; j < 4; j++)
                bfr[j] = *(const bf16x8*)&Bs[(wn + j * 16 + lr) * 72 + k2 + lk];
            #pragma unroll
            for (int i = 0; i < 4; i++)
                #pragma unroll
                for (int j = 0; j < 4; j++)
                    acc[i][j] = __builtin_amdgcn_mfma_f32_16x16x32_bf16(a[i], bfr[j], acc[i][j], 0, 0, 0);
        }
        __syncthreads();
    }
    const int r0 = (lane >> 4) * 4;
    #pragma unroll
    for (int j = 0; j < 4; j++) {
        int col = bn + wn + j * 16 + lr;
        float bv = bias ? bias[col] : 0.f;
        #pragma unroll
        for (int i = 0; i < 4; i++) {
            int row = bm + wm + i * 16 + r0;
            #pragma unroll
            for (int q = 0; q < 4; q++) {
                float v = acc[i][j][q] + bv;
                if (mode == 0) ((float*)Cv)[(size_t)(row + q) * ldc + col] = v;
                else ((ushort_t*)Cv)[(size_t)(row + q) * ldc + col] = f2bf(tanh_(v));
            }
        }
    }
}

// ---------------- context mean ----------------
__global__ void mean_ctx(const float* __restrict__ e1, float* __restrict__ ctx) {
    int g = blockIdx.x * 256 + threadIdx.x; // 16384
    int b = g >> 9, u = g & 511;
    float s = 0.f;
    #pragma unroll 8
    for (int t = 0; t < TT; t++) s += e1[((size_t)b * TT + t) * HH + u];
    ctx[g] = s * (1.f / 64.f);
}

// ---- tagged poll primitives (v6-verified protocol) ----
#define LOADS16                                                            \
        "global_load_dwordx2 %0, %16, off sc0 sc1\n\t"                     \
        "global_load_dwordx2 %1, %16, off offset:256 sc0 sc1\n\t"          \
        "global_load_dwordx2 %2, %16, off offset:512 sc0 sc1\n\t"          \
        "global_load_dwordx2 %3, %16, off offset:768 sc0 sc1\n\t"          \
        "global_load_dwordx2 %4, %16, off offset:1024 sc0 sc1\n\t"         \
        "global_load_dwordx2 %5, %16, off offset:1280 sc0 sc1\n\t"         \
        "global_load_dwordx2 %6, %16, off offset:1536 sc0 sc1\n\t"         \
        "global_load_dwordx2 %7, %16, off offset:1792 sc0 sc1\n\t"         \
        "global_load_dwordx2 %8, %16, off offset:2048 sc0 sc1\n\t"         \
        "global_load_dwordx2 %9, %16, off offset:2304 sc0 sc1\n\t"         \
        "global_load_dwordx2 %10, %16, off offset:2560 sc0 sc1\n\t"        \
        "global_load_dwordx2 %11, %16, off offset:2816 sc0 sc1\n\t"        \
        "global_load_dwordx2 %12, %16, off offset:3072 sc0 sc1\n\t"        \
        "global_load_dwordx2 %13, %16, off offset:3328 sc0 sc1\n\t"        \
        "global_load_dwordx2 %14, %16, off offset:3584 sc0 sc1\n\t"        \
        "global_load_dwordx2 %15, %16, off offset:3840 sc0 sc1\n\t"

#define OUTS16(a) "=&v"(a[0]), "=&v"(a[1]), "=&v"(a[2]), "=&v"(a[3]),      \
                  "=&v"(a[4]), "=&v"(a[5]), "=&v"(a[6]), "=&v"(a[7]),      \
                  "=&v"(a[8]), "=&v"(a[9]), "=&v"(a[10]), "=&v"(a[11]),    \
                  "=&v"(a[12]), "=&v"(a[13]), "=&v"(a[14]), "=&v"(a[15])

__device__ __forceinline__ bool tag_ok16(const uint2* q, unsigned int tag) {
    unsigned int a = 0xFFFFFFFFu, o = 0u;
    #pragma unroll
    for (int i = 0; i < 16; i++) { a &= q[i].x & q[i].y; o |= q[i].x | q[i].y; }
    return ((a >> 16) == tag) & ((o >> 16) == tag);
}

__device__ __forceinline__ void poll16_f32(const uint2* rp, unsigned int tag, float* hd) {
    uint2 q[16];
    bool ok;
    do {
        asm volatile(LOADS16 "s_waitcnt vmcnt(0)"
                     : OUTS16(q) : "v"(rp) : "memory");
        __builtin_amdgcn_sched_barrier(0);
        ok = tag_ok16(q, tag);
    } while (!ok);
    #pragma unroll
    for (int i = 0; i < 16; i++)
        hd[32 * i] = __uint_as_float((q[i].x << 16) | (q[i].y & 0xFFFFu));
}
__device__ __forceinline__ void poll16_bf16(const uint2* rp, unsigned int tag, ushort_t* hd) {
    uint2 q[16];
    bool ok;
    do {
        asm volatile(LOADS16 "s_waitcnt vmcnt(0)"
                     : OUTS16(q) : "v"(rp) : "memory");
        __builtin_amdgcn_sched_barrier(0);
        ok = tag_ok16(q, tag);
    } while (!ok);
    #pragma unroll
    for (int i = 0; i < 16; i++)
        hd[32 * i] = f2bf(__uint_as_float((q[i].x << 16) | (q[i].y & 0xFFFFu)));
}
// poll + exact fp32 -> (bf16 hi, bf16 lo) split staging (split at consumption)
__device__ __forceinline__ void poll16_hilo(const uint2* rp, unsigned int tag,
                                            ushort_t* hh, ushort_t* hl) {
    uint2 q[16];
    bool ok;
    do {
        asm volatile(LOADS16 "s_waitcnt vmcnt(0)"
                     : OUTS16(q) : "v"(rp) : "memory");
        __builtin_amdgcn_sched_barrier(0);
        ok = tag_ok16(q, tag);
    } while (!ok);
    #pragma unroll
    for (int i = 0; i < 16; i++) {
        float v = __uint_as_float((q[i].x << 16) | (q[i].y & 0xFFFFu));
        ushort_t hi, lo; split_bf(v, hi, lo);
        hh[32 * i] = hi; hl[32 * i] = lo;
    }
}

// ---------------- fused layer-pair scan (v14 = v9 + L1 recurrence on MFMA) -----------
// 256 blocks x 512 threads: blocks 0..127 = layer0 (v9 fp32-dot scan), 128..255 =
// layer1. L1: BOTH projections via register-stationary bf16 MFMA — Wih1 plain bf16
// (feed-forward, r8-proven) + Whh1 hi/lo split (3-term, r4-E2E-verified) — h0(t) in ah,
// h1(t-1) in ahh/ahl (exact fp32 split at ring consumption). One acc accumulates all
// terms -> pglds; pointwise = bias + 4 partial sums. Tail: v9 serial polls.
__global__ __launch_bounds__(512) void scan_pair2(
    const float* __restrict__ gatesX0,  // [B*T][4H] layer0 x-proj incl bias
    const float* __restrict__ ctxAdd0,  // [B][4H] or null (decoder layer0)
    const float* __restrict__ Whh0,     // [4H][H]
    const float* __restrict__ Wih1,     // [4H][H] (-> register fragments, bf16)
    const float* __restrict__ Whh1,     // [4H][H] (-> register fragments, bf16 hi/lo)
    const float* __restrict__ b1,       // [4H]
    const float* __restrict__ h00, int sh00, const float* __restrict__ c00, int sc00,
    const float* __restrict__ h01, int sh01, const float* __restrict__ c01, int sc01,
    float* __restrict__ out0, float* __restrict__ out1,
    float* __restrict__ cT0o, float* __restrict__ cT1o,
    uint2* __restrict__ ring0, uint2* __restrict__ ring1,
    int tb0, int tb1)
{
    __shared__ float wlds[32 * 516];    // L0: Whh0 slice (fp32)
    __shared__ float hmain[16 * 516];   // L0: h0(t-1)
    __shared__ float glds[16 * 36];     // L0: h-dot results [batch][row]
    __shared__ ushort_t ah[16 * 520];   // L1: h0(t) bf16 (xproj A-operand)
    __shared__ ushort_t ahh[16 * 520];  // L1: h1(t-1) bf16 hi
    __shared__ ushort_t ahl[16 * 520];  // L1: h1(t-1) bf16 lo
    __shared__ float pglds[8 * 256];    // L1: MFMA partials [kh*2+ni][batch*16+col]
    const int tid = threadIdx.x;
    const bool isL1 = blockIdx.x >= 128;
    const int rb = blockIdx.x & 127;
    const int bg = rb >> 6, ub = rb & 63, u0 = ub * 8;
    const int w = tid >> 6, l = tid & 63;
    const int bb = l >> 2, rr = w * 4 + (l & 3);       // L0 dot role
    const int grow = (rr >> 3) * HH + u0 + (rr & 7);
    const int batch = bg * 16 + bb;
    const int srow = tid >> 5, hc0 = tid & 31;         // staging role

    if (!isL1) { // stationary Whh0 -> LDS (L0 only)
        const int sr = tid >> 4, ch = (tid & 15) * 32;
        const float* ws = Whh0 + (size_t)((sr >> 3) * HH + u0 + (sr & 7)) * HH + ch;
        float* wd = &wlds[sr * 516 + ch];
        #pragma unroll
        for (int j = 0; j < 32; j += 4) *(f32x4*)(wd + j) = *(const f32x4*)(ws + j);
    }
    // L1: stationary register fragments. Wave (ni,kh); v9-verified geometry.
    const int ni = w & 1, kh = w >> 1, lr = l & 15, ls = l >> 4;
    bf16x8 bfrag[4], wh_hi[4], wh_lo[4];
    if (isL1) {
        const int nrow = ni * 16 + lr;
        const int gN = (nrow >> 3) * HH + u0 + (nrow & 7);
        const float* wr = Wih1 + (size_t)gN * HH + kh * 128 + ls * 8;
        const float* wr2 = Whh1 + (size_t)gN * HH + kh * 128 + ls * 8;
        #pragma unroll
        for (int kk = 0; kk < 4; kk++) {
            float f[8];
            *(f32x4*)&f[0] = *(const f32x4*)(wr + kk * 32);
            *(f32x4*)&f[4] = *(const f32x4*)(wr + kk * 32 + 4);
            bf16x8 hv;
            #pragma unroll
            for (int j = 0; j < 8; j++) hv[j] = (short)f2bf(f[j]);
            bfrag[kk] = hv;
            *(f32x4*)&f[0] = *(const f32x4*)(wr2 + kk * 32);
            *(f32x4*)&f[4] = *(const f32x4*)(wr2 + kk * 32 + 4);
            bf16x8 hv2, lv2;
            #pragma unroll
            for (int j = 0; j < 8; j++) {
                ushort_t hu2, lu2; split_bf(f[j], hu2, lu2);
                hv2[j] = (short)hu2; lv2[j] = (short)lu2;
            }
            wh_hi[kk] = hv2; wh_lo[kk] = lv2;
        }
    }
    { // initial own-recurrence h
        if (!isL1) {
            const float* hs = h00 + (size_t)(bg * 16 + srow) * sh00;
            float* hd = &hmain[srow * 516 + hc0];
            #pragma unroll
            for (int j = 0; j < 16; j++) hd[32 * j] = hs[hc0 + 32 * j];
        } else {
            const float* hs = h01 + (size_t)(bg * 16 + srow) * sh01;
            ushort_t* hh = &ahh[srow * 520 + hc0];
            ushort_t* hl = &ahl[srow * 520 + hc0];
            #pragma unroll
            for (int j = 0; j < 16; j++) {
                ushort_t hi2, lo2; split_bf(hs[hc0 + 32 * j], hi2, lo2);
                hh[32 * j] = hi2; hl[32 * j] = lo2;
            }
        }
    }
    // pointwise-thread state
    const int pb = tid >> 3, pu = tid & 7, gbatch = bg * 16 + pb;
    float creg = 0.f, b1v0 = 0.f, b1v1 = 0.f, b1v2 = 0.f, b1v3 = 0.f;
    if (tid < 128) {
        const float* ci = isL1 ? c01 : c00;
        const int cs = isL1 ? sc01 : sc00;
        creg = ci[(size_t)gbatch * cs + u0 + pu];
        if (isL1) {
            b1v0 = b1[0 * HH + u0 + pu]; b1v1 = b1[1 * HH + u0 + pu];
            b1v2 = b1[2 * HH + u0 + pu]; b1v3 = b1[3 * HH + u0 + pu];
        }
    }
    float xctx = 0.f, gx_cur = 0.f, gx_nxt = 0.f;
    const float* gxp = nullptr;
    if (!isL1) {
        gxp = gatesX0 + (size_t)batch * TT * G4H + grow;
        gx_cur = gxp[0];
        if (ctxAdd0) xctx = ctxAdd0[(size_t)batch * G4H + grow];
    } else {
        // h0(0) from L0's first publish
        const uint2* rp = ring0 + ((size_t)0 * BB + bg * 16 + srow) * HH + hc0;
        poll16_bf16(rp, (unsigned int)(tb0 + 1), &ah[srow * 520 + hc0]);
    }
    float* outp = isL1 ? out1 : out0;
    uint2* ringp = isL1 ? ring1 : ring0;
    const int tbase = isL1 ? tb1 : tb0;

    for (int t = 0; t < TT; ++t) {
        __syncthreads();   // staged inputs ready; prev partials consumed
        if (!isL1) {
            int tn = (t + 1 < TT) ? t + 1 : t;
            gx_nxt = gxp[(size_t)tn * G4H];
            f32x4 s = {0.f, 0.f, 0.f, 0.f};
            const float* hp = &hmain[bb * 516];
            const float* wp = &wlds[rr * 516];
            #pragma unroll 8
            for (int k = 0; k < HH; k += 4) {
                f32x4 hv = *(const f32x4*)(hp + k);
                f32x4 wv = *(const f32x4*)(wp + k);
                s.x = fmaf(hv.x, wv.x, s.x); s.y = fmaf(hv.y, wv.y, s.y);
                s.z = fmaf(hv.z, wv.z, s.z); s.w = fmaf(hv.w, wv.w, s.w);
            }
            glds[bb * 36 + rr] = gx_cur + xctx + ((s.x + s.y) + (s.z + s.w));
        } else {
            // all projections via MFMA: xproj (plain bf16) + recurrence (hi/lo 3-term)
            f32x4 acc = {0.f, 0.f, 0.f, 0.f};
            const int abase = lr * 520 + kh * 128 + ls * 8;
            const ushort_t* ab  = &ah[abase];
            const ushort_t* abh = &ahh[abase];
            const ushort_t* abl = &ahl[abase];
            #pragma unroll
            for (int kk = 0; kk < 4; kk++) {
                bf16x8 av = *(const bf16x8*)(ab + kk * 32);
                acc = __builtin_amdgcn_mfma_f32_16x16x32_bf16(av, bfrag[kk], acc, 0, 0, 0);
                bf16x8 hhv = *(const bf16x8*)(abh + kk * 32);
                bf16x8 hlv = *(const bf16x8*)(abl + kk * 32);
                acc = __builtin_amdgcn_mfma_f32_16x16x32_bf16(hhv, wh_hi[kk], acc, 0, 0, 0);
                acc = __builtin_amdgcn_mfma_f32_16x16x32_bf16(hlv, wh_hi[kk], acc, 0, 0, 0);
                acc = __builtin_amdgcn_mfma_f32_16x16x32_bf16(hhv, wh_lo[kk], acc, 0, 0, 0);
            }
            #pragma unroll
            for (int q = 0; q < 4; q++)
                pglds[(kh * 2 + ni) * 256 + (ls * 4 + q) * 16 + lr] = acc[q];
        }
        __syncthreads();
        const unsigned int tag = (unsigned int)(tbase + t + 1);
        if (tid < 128) {
            float pre[4];
            if (!isL1) {
                #pragma unroll
                for (int g = 0; g < 4; g++) pre[g] = glds[pb * 36 + g * 8 + pu];
            } else {
                float bv[4] = {b1v0, b1v1, b1v2, b1v3};
                #pragma unroll
                for (int g = 0; g < 4; g++) {
                    int r = g * 8 + pu;
                    int nit = r >> 4, cr = r & 15;
                    float p = bv[g];
                    #pragma unroll
                    for (int k2 = 0; k2 < 4; k2++)
                        p += pglds[(k2 * 2 + nit) * 256 + pb * 16 + cr];
                    pre[g] = p;
                }
            }
            float c = sigf(pre[1]) * creg + sigf(pre[0]) * tanh_(pre[2]);
            float h = sigf(pre[3]) * tanh_(c);
            creg = c;
            outp[((size_t)gbatch * TT + t) * HH + u0 + pu] = h;
            unsigned int hu = __float_as_uint(h);
            uint2 wv2;
            wv2.x = (tag << 16) | (hu >> 16);
            wv2.y = (tag << 16) | (hu & 0xFFFFu);
            uint2* pp = ringp + ((size_t)t * BB + gbatch) * HH + u0 + pu;
            asm volatile("global_store_dwordx2 %0, %1, off sc0 sc1"
                         :: "v"(pp), "v"(wv2) : "memory");
            if (t == TT - 1) {
                if (!isL1 && cT0o) cT0o[(size_t)gbatch * HH + u0 + pu] = c;
                if (isL1 && cT1o)  cT1o[(size_t)gbatch * HH + u0 + pu] = c;
            }
        }
        if (t + 1 < TT) {
            if (!isL1) {
                const uint2* rp = ring0 + ((size_t)t * BB + bg * 16 + srow) * HH + hc0;
                poll16_f32(rp, tag, &hmain[srow * 516 + hc0]);
            } else {
                const uint2* rp1 = ring1 + ((size_t)t * BB + bg * 16 + srow) * HH + hc0;
                poll16_hilo(rp1, tag, &ahh[srow * 520 + hc0], &ahl[srow * 520 + hc0]);
                const uint2* rp0 = ring0 + ((size_t)(t + 1) * BB + bg * 16 + srow) * HH + hc0;
                poll16_bf16(rp0, (unsigned int)(tb0 + t + 2), &ah[srow * 520 + hc0]);
            }
        }
        gx_cur = gx_nxt;
    }
}

// ---------------- final projection: bf16 MFMA GEMM, C = A*B^T + bias ----------------
__global__ __launch_bounds__(256) void gemm_bf16(
    const ushort_t* __restrict__ A,
    const float* __restrict__ B,
    const float* __restrict__ bias,
    float* __restrict__ C, int M, int N, int K)
{
    __shared__ ushort_t As[128 * 72];
    __shared__ ushort_t Bs[128 * 72];
    const int tid = threadIdx.x;
    const int bm = blockIdx.x * 128, bn = blockIdx.y * 128;
    const int lane = tid & 63, wave = tid >> 6;
    const int wm = (wave & 1) * 64, wn = (wave >> 1) * 64;
    const int lr = lane & 15, lk = (lane >> 4) * 8;
    const int srow = tid >> 3, sch = tid & 7;
    f32x4 acc[4][4] = {};

    for (int k0 = 0; k0 < K; k0 += 64) {
        #pragma unroll
        for (int rr = 0; rr < 4; rr++) {
            int row = srow + rr * 32;
            const ushort_t* as = A + (size_t)(bm + row) * K + k0 + sch * 8;
            *(int4*)&As[row * 72 + sch * 8] = *(const int4*)as;
            const float* bs = B + (size_t)(bn + row) * K + k0 + sch * 8;
            float4 f0 = *(const float4*)bs;
            float4 f1 = *(const float4*)(bs + 4);
            int4 pk;
            pk.x = (int)f2bf(f0.x) | ((int)f2bf(f0.y) << 16);
            pk.y = (int)f2bf(f0.z) | ((int)f2bf(f0.w) << 16);
            pk.z = (int)f2bf(f1.x) | ((int)f2bf(f1.y) << 16);
            pk.w = (int)f2bf(f1.z) | ((int)f2bf(f1.w) << 16);
            *(int4*)&Bs[row * 72 + sch * 8] = pk;
        }
        __syncthreads();
        #pragma unroll
        for (int k2 = 0; k2 < 64; k2 += 32) {
            bf16x8 a[4], bfr[4];
            #pragma unroll
            for (int i = 0; i < 4; i++)
                a[i] = *(const bf16x8*)&As[(wm + i * 16 + lr) * 72 + k2 + lk];
            #pragma unroll
            for (int j = 0; j < 4; j++)
                bfr[j] = *(const bf16x8*)&Bs[(wn + j * 16 + lr) * 72 + k2 + lk];
            #pragma unroll
            for (int i = 0; i < 4; i++)
                #pragma unroll
                for (int j = 0; j < 4; j++)
                    acc[i][j] = __builtin_amdgcn_mfma_f32_16x16x32_bf16(a[i], bfr[j], acc[i][j], 0, 0, 0);
        }
        __syncthreads();
    }
    const int r0 = (lane >> 4) * 4;
    #pragma unroll
    for (int j = 0; j < 4; j++) {
        int col = bn + wn + j * 16 + lr;
        float bv = bias[col];
        #pragma unroll
        for (int i = 0; i < 4; i++) {
            int row = bm + wm + i * 16 + r0;
            #pragma unroll
            for (int q = 0; q < 4; q++)
                C[(size_t)(row + q) * N + col] = acc[i][j][q] + bv;
        }
    }
}

extern "C" void kernel_launch(void* const* d_in, const int* in_sizes, int n_in,
                              void* d_out, int out_size, void* d_ws, size_t ws_size,
                              hipStream_t stream) {
    const int*   src      = (const int*)d_in[0];
    const int*   tgt      = (const int*)d_in[1];
    const float* enc_emb  = (const float*)d_in[2];
    const float* dec_emb  = (const float*)d_in[3];
    const float* eWih0    = (const float*)d_in[4];
    const float* eWhh0    = (const float*)d_in[5];
    const float* eb0      = (const float*)d_in[6];
    const float* eWih1    = (const float*)d_in[7];
    const float* eWhh1    = (const float*)d_in[8];
    const float* eb1      = (const float*)d_in[9];
    const float* dWih0    = (const float*)d_in[10];
    const float* dWhh0    = (const float*)d_in[11];
    const float* db0      = (const float*)d_in[12];
    const float* dWih1    = (const float*)d_in[13];
    const float* dWhh1    = (const float*)d_in[14];
    const float* db1      = (const float*)d_in[15];
    const float* pW1      = (const float*)d_in[16];
    const float* pb1      = (const float*)d_in[17];
    const float* pW2      = (const float*)d_in[18];
    const float* pb2      = (const float*)d_in[19];
    float* out = (float*)d_out;

    // workspace carve (small persistent buffers)
    float* fws   = (float*)d_ws;
    float* zeros = fws;                        // 512 f (padded to 1024)
    float* cT0   = fws + 2048;                 // 16384 f
    float* cT1   = cT0 + 16384;
    float* ctx   = cT1 + 16384;
    float* ctxW  = ctx + 16384;                // 65536 f
    ushort_t* hid = (ushort_t*)(ctxW + 65536); // 2048*512 bf16

    // d_out scratch (all dead before final projection writes everything)
    float* G0  = out;                 // 2048*2048 gate buffers
    float* G1  = G0 + 4194304;        // (unused; layout kept)
    float* G2  = G1 + 4194304;
    float* G3  = G2 + 4194304;        // (unused)
    float* xe  = G3 + 4194304;        // 2048*256
    float* xd  = xe + 524288;
    float* e0  = xd + 524288;         // 2048*512
    float* e1  = e0 + 1048576;
    float* d0  = e1 + 1048576;
    float* d1v = d0 + 1048576;
    uint2* ring0 = (uint2*)(d1v + 1048576);  // [64][32][512] tagged h (8 MB)
    uint2* ring1 = ring0 + 1048576;          // [64][32][512] tagged h (8 MB)

    zero_init<<<1, 256, 0, stream>>>(zeros);
    gather_rows<<<2048, 64, 0, stream>>>(src, enc_emb, xe);
    gather_rows<<<2048, 64, 0, stream>>>(tgt, dec_emb, xd);

    // layer-0 input projections (K=256, MFMA)
    gemm_mfma<<<dim3(16, 16), 256, 0, stream>>>(xe, 256, eWih0, 256, eb0, G0, 2048, 256, 0);
    gemm_mfma<<<dim3(16, 16), 256, 0, stream>>>(xd, 256, dWih0, 768, db0, G2, 2048, 256, 0);

    // fused encoder pair (enc0 + enc1 pipelined, skew 1)
    scan_pair2<<<256, 512, 0, stream>>>(
        G0, nullptr, eWhh0, eWih1, eWhh1, eb1,
        zeros, 0, zeros, 0, zeros, 0, zeros, 0,
        e0, e1, cT0, cT1, ring0, ring1, 0, 64);

    // context
    mean_ctx<<<64, 256, 0, stream>>>(e1, ctx);
    gemm_f32<<<dim3(32, 1), 256, 0, stream>>>(ctx, 512, dWih0 + 256, 768, nullptr, ctxW, 2048, 32, 2048, 512, 0);

    // fused decoder pair
    scan_pair2<<<256, 512, 0, stream>>>(
        G2, ctxW, dWhh0, dWih1, dWhh1, db1,
        e0 + 63 * 512, 64 * 512, cT0, 512,
        e1 + 63 * 512, 64 * 512, cT1, 512,
        d0, d1v, nullptr, nullptr, ring0, ring1, 128, 192);

    // projection: hid = tanh(d1*W1^T + b1) (MFMA, bf16 out); logits = hid*W2^T + b2
    gemm_mfma<<<dim3(16, 4), 256, 0, stream>>>(d1v, 512, pW1, 512, pb1, hid, 512, 512, 2);
    gemm_bf16<<<dim3(16, 250), 256, 0, stream>>>(hid, pW2, pb2, out, 2048, 32000, 512);
}